// Round 3
// baseline (1293.911 us; speedup 1.0000x reference)
//
#include <hip/hip_runtime.h>
#include <hip/hip_bf16.h>

#define RNUM 8
#define HH1 32
#define HH2 16
#define FIN 128
#define NPB 16
#define BNODES 256      // nodes per bucket
#define NBMAX 512
#define PCHUNK 8192     // edges per partition block

// --- bucket histogram (bucket = dst >> 8) ---
__global__ __launch_bounds__(256) void k_bhist(const int* __restrict__ ei,
    int* __restrict__ ghist, int E, int NB) {
  __shared__ int h[NBMAX];
  int t = threadIdx.x;
  for (int i = t; i < NBMAX; i += 256) h[i] = 0;
  __syncthreads();
  int base = blockIdx.x * 4096;
  #pragma unroll
  for (int j = 0; j < 16; ++j) {
    int e = base + j * 256 + t;
    if (e < E) atomicAdd(&h[ei[E + e] >> 8], 1);
  }
  __syncthreads();
  for (int i = t; i < NB; i += 256)
    if (h[i]) atomicAdd(&ghist[i], h[i]);
}

// --- exclusive scan of bucket counts -> bbase, init gcursor ---
__global__ __launch_bounds__(NBMAX) void k_bscan(const int* __restrict__ ghist,
    int* __restrict__ bbase, int* __restrict__ gcursor, int NB, int E) {
  __shared__ int buf[NBMAX];
  int t = threadIdx.x;
  int v = (t < NB) ? ghist[t] : 0;
  buf[t] = v;
  __syncthreads();
  for (int d = 1; d < NBMAX; d <<= 1) {
    int w = (t >= d) ? buf[t - d] : 0;
    __syncthreads();
    buf[t] += w;
    __syncthreads();
  }
  if (t < NB) {
    int ex = buf[t] - v;
    bbase[t] = ex;
    gcursor[t] = ex;
  }
  if (t == 0) bbase[NB] = E;
}

// --- partition edges into buckets with coalesced writes ---
__global__ __launch_bounds__(512) void k_part(const int* __restrict__ ei,
    const int* __restrict__ ea, int* __restrict__ gcursor,
    unsigned* __restrict__ ebuf, int E, int NB) {
  __shared__ unsigned reorder[PCHUNK];
  __shared__ unsigned short bkt[PCHUNK];
  __shared__ int hist[NBMAX], startl[NBMAX], cursor[NBMAX], gb[NBMAX], scanb[NBMAX];
  int t = threadIdx.x;
  int base = blockIdx.x * PCHUNK;
  int cn = min(PCHUNK, E - base);
  unsigned key[16];
  short bb[16];
  hist[t] = 0;
  __syncthreads();
  #pragma unroll
  for (int j = 0; j < 16; ++j) {
    int e = base + j * 512 + t;
    bb[j] = -1;
    if (e < E) {
      int src = ei[e], dst = ei[E + e], rel = ea[e];
      key[j] = ((unsigned)(dst & (BNODES - 1)) << 20) | ((unsigned)src << 3) | (unsigned)rel;
      int b = dst >> 8;
      bb[j] = (short)b;
      atomicAdd(&hist[b], 1);
    }
  }
  __syncthreads();
  int v = hist[t];
  scanb[t] = v;
  __syncthreads();
  for (int d = 1; d < NBMAX; d <<= 1) {
    int w = (t >= d) ? scanb[t - d] : 0;
    __syncthreads();
    scanb[t] += w;
    __syncthreads();
  }
  startl[t] = scanb[t] - v;
  cursor[t] = scanb[t] - v;
  __syncthreads();
  #pragma unroll
  for (int j = 0; j < 16; ++j) {
    if (bb[j] >= 0) {
      int pos = atomicAdd(&cursor[bb[j]], 1);
      reorder[pos] = key[j];
      bkt[pos] = (unsigned short)bb[j];
    }
  }
  __syncthreads();
  if (t < NB && hist[t] > 0) gb[t] = atomicAdd(&gcursor[t], hist[t]);
  __syncthreads();
  for (int p = t; p < cn; p += 512) {
    int b = bkt[p];
    ebuf[gb[b] + (p - startl[b])] = reorder[p];
  }
}

// xw1[n][r*32+h] (bf16) = x@W1 ; agg1[n][h] = x@root1 + b1
__global__ __launch_bounds__(256) void k_gemm1(const float* __restrict__ x,
    const float* __restrict__ W, const float* __restrict__ root,
    const float* __restrict__ b, __hip_bfloat16* __restrict__ xw,
    float* __restrict__ agg, int N) {
  __shared__ float xs[NPB][FIN];
  int n0 = blockIdx.x * NPB;
  int t = threadIdx.x;
  #pragma unroll
  for (int rep = 0; rep < 2; ++rep) {
    int q = t + rep * 256;
    int n = q >> 5;
    int i0 = (q & 31) << 2;
    int nn = n0 + n;
    float4 v = make_float4(0.f, 0.f, 0.f, 0.f);
    if (nn < N) v = *(const float4*)(x + (size_t)nn * FIN + i0);
    *(float4*)(&xs[n][i0]) = v;
  }
  __syncthreads();

  float acc[NPB];
  #pragma unroll
  for (int n = 0; n < NPB; ++n) acc[n] = 0.f;
  const float* Wc = W + ((t >> 5) * FIN * HH1) + (t & 31);
  #pragma unroll 4
  for (int i = 0; i < FIN; ++i) {
    float w = Wc[(size_t)i * HH1];
    #pragma unroll
    for (int n = 0; n < NPB; ++n) acc[n] = fmaf(w, xs[n][i], acc[n]);
  }
  #pragma unroll
  for (int n = 0; n < NPB; ++n) {
    int nn = n0 + n;
    if (nn < N) xw[(size_t)nn * (RNUM * HH1) + t] = __float2bfloat16(acc[n]);
  }

  int c = t & 31;
  int nr = t >> 5;
  float r0 = 0.f, r1 = 0.f;
  const float* Rc = root + c;
  #pragma unroll 4
  for (int i = 0; i < FIN; ++i) {
    float w = Rc[(size_t)i * HH1];
    r0 = fmaf(w, xs[nr][i], r0);
    r1 = fmaf(w, xs[nr + 8][i], r1);
  }
  float bb = b[c];
  int nn0 = n0 + nr, nn1 = n0 + nr + 8;
  if (nn0 < N) agg[(size_t)nn0 * HH1 + c] = r0 + bb;
  if (nn1 < N) agg[(size_t)nn1 * HH1 + c] = r1 + bb;
}

// one block per bucket: LDS-resident agg over 256 nodes x 32 h
__global__ __launch_bounds__(512) void k_agg1(const int* __restrict__ bbase,
    const unsigned* __restrict__ ebuf, const __hip_bfloat16* __restrict__ xw,
    float* __restrict__ agg, int N) {
  __shared__ float aggl[BNODES * 33];        // padded stride 33
  __shared__ float invl[BNODES * RNUM];
  int t = threadIdx.x;
  int b = blockIdx.x;
  int n0 = b << 8;
  int s = bbase[b], e = bbase[b + 1];
  for (int i = t; i < BNODES * 33; i += 512) aggl[i] = 0.f;
  int* cntl = (int*)invl;
  for (int i = t; i < BNODES * RNUM; i += 512) cntl[i] = 0;
  __syncthreads();
  for (int p = s + t; p < e; p += 512) {
    unsigned k = ebuf[p];
    atomicAdd(&cntl[((k >> 20) << 3) | (k & 7u)], 1);
  }
  __syncthreads();
  for (int i = t; i < BNODES * RNUM; i += 512) {
    int c = cntl[i];
    invl[i] = 1.0f / (float)(c > 1 ? c : 1);
  }
  __syncthreads();
  for (int p = s + t; p < e; p += 512) {
    unsigned k = ebuf[p];
    int dl = (int)(k >> 20);
    unsigned idx = k & 0xFFFFFu;
    float w = invl[(dl << 3) | (k & 7u)];
    const unsigned short* row = (const unsigned short*)(xw + ((size_t)idx << 5));
    uint4 q0 = *(const uint4*)(row);
    uint4 q1 = *(const uint4*)(row + 8);
    uint4 q2 = *(const uint4*)(row + 16);
    uint4 q3 = *(const uint4*)(row + 24);
    unsigned u[16] = {q0.x, q0.y, q0.z, q0.w, q1.x, q1.y, q1.z, q1.w,
                      q2.x, q2.y, q2.z, q2.w, q3.x, q3.y, q3.z, q3.w};
    float* bp = &aggl[dl * 33];
    #pragma unroll
    for (int p2 = 0; p2 < 16; ++p2) {
      unsigned uu = u[p2];
      atomicAdd(&bp[2 * p2],     w * __uint_as_float(uu << 16));
      atomicAdd(&bp[2 * p2 + 1], w * __uint_as_float(uu & 0xFFFF0000u));
    }
  }
  __syncthreads();
  for (int i = t; i < BNODES * HH1; i += 512) {
    int dl = i >> 5, h = i & 31;
    int nn = n0 + dl;
    if (nn < N) agg[((size_t)nn << 5) + h] += aggl[dl * 33 + h];
  }
}

// reads relu(agg1); xw2 (bf16) = h1@W2 ; agg2 = h1@root2 + b2
__global__ __launch_bounds__(256) void k_gemm2(const float* __restrict__ agg1,
    const float* __restrict__ W, const float* __restrict__ root,
    const float* __restrict__ b, __hip_bfloat16* __restrict__ xw,
    float* __restrict__ agg, int N) {
  __shared__ float hs[NPB][HH1];
  int n0 = blockIdx.x * NPB;
  int t = threadIdx.x;
  {
    int n = t >> 4;
    int i0 = (t & 15) << 1;
    int nn = n0 + n;
    float2 v = make_float2(0.f, 0.f);
    if (nn < N) v = *(const float2*)(agg1 + (size_t)nn * HH1 + i0);
    hs[n][i0] = fmaxf(v.x, 0.f);
    hs[n][i0 + 1] = fmaxf(v.y, 0.f);
  }
  __syncthreads();

  int c = t & 127;
  int ns = t >> 7;
  const float* Wc = W + ((c >> 4) * HH1 * HH2) + (c & 15);
  float acc[8];
  #pragma unroll
  for (int k = 0; k < 8; ++k) acc[k] = 0.f;
  #pragma unroll 4
  for (int i = 0; i < HH1; ++i) {
    float w = Wc[(size_t)i * HH2];
    #pragma unroll
    for (int k = 0; k < 8; ++k) acc[k] = fmaf(w, hs[ns + 2 * k][i], acc[k]);
  }
  #pragma unroll
  for (int k = 0; k < 8; ++k) {
    int nn = n0 + ns + 2 * k;
    if (nn < N) xw[(size_t)nn * (RNUM * HH2) + c] = __float2bfloat16(acc[k]);
  }

  int c2 = t & 15;
  int n = t >> 4;
  float r0 = 0.f;
  const float* Rc = root + c2;
  #pragma unroll 4
  for (int i = 0; i < HH1; ++i) r0 = fmaf(Rc[(size_t)i * HH2], hs[n][i], r0);
  int nn = n0 + n;
  if (nn < N) agg[(size_t)nn * HH2 + c2] = r0 + b[c2];
}

__global__ __launch_bounds__(512) void k_agg2(const int* __restrict__ bbase,
    const unsigned* __restrict__ ebuf, const __hip_bfloat16* __restrict__ xw,
    float* __restrict__ agg, int N) {
  __shared__ float aggl[BNODES * 17];        // padded stride 17
  __shared__ float invl[BNODES * RNUM];
  int t = threadIdx.x;
  int b = blockIdx.x;
  int n0 = b << 8;
  int s = bbase[b], e = bbase[b + 1];
  for (int i = t; i < BNODES * 17; i += 512) aggl[i] = 0.f;
  int* cntl = (int*)invl;
  for (int i = t; i < BNODES * RNUM; i += 512) cntl[i] = 0;
  __syncthreads();
  for (int p = s + t; p < e; p += 512) {
    unsigned k = ebuf[p];
    atomicAdd(&cntl[((k >> 20) << 3) | (k & 7u)], 1);
  }
  __syncthreads();
  for (int i = t; i < BNODES * RNUM; i += 512) {
    int c = cntl[i];
    invl[i] = 1.0f / (float)(c > 1 ? c : 1);
  }
  __syncthreads();
  for (int p = s + t; p < e; p += 512) {
    unsigned k = ebuf[p];
    int dl = (int)(k >> 20);
    unsigned idx = k & 0xFFFFFu;
    float w = invl[(dl << 3) | (k & 7u)];
    const unsigned short* row = (const unsigned short*)(xw + ((size_t)idx << 4));
    uint4 q0 = *(const uint4*)(row);
    uint4 q1 = *(const uint4*)(row + 8);
    unsigned u[8] = {q0.x, q0.y, q0.z, q0.w, q1.x, q1.y, q1.z, q1.w};
    float* bp = &aggl[dl * 17];
    #pragma unroll
    for (int p2 = 0; p2 < 8; ++p2) {
      unsigned uu = u[p2];
      atomicAdd(&bp[2 * p2],     w * __uint_as_float(uu << 16));
      atomicAdd(&bp[2 * p2 + 1], w * __uint_as_float(uu & 0xFFFF0000u));
    }
  }
  __syncthreads();
  for (int i = t; i < BNODES * HH2; i += 512) {
    int dl = i >> 4, h = i & 15;
    int nn = n0 + dl;
    if (nn < N) agg[((size_t)nn << 4) + h] += aggl[dl * 17 + h];
  }
}

__global__ __launch_bounds__(256) void k_pool(const float* __restrict__ agg2,
    const int* __restrict__ batch, unsigned* __restrict__ pooled, int N) {
  int gid = blockIdx.x * 256 + threadIdx.x;
  int n = gid >> 4;
  if (n < N) {
    int h = gid & 15;
    float v = fmaxf(agg2[(size_t)n * HH2 + h], 0.f);
    atomicMax(&pooled[batch[n] * HH2 + h], __float_as_uint(v));
  }
}

__global__ __launch_bounds__(256) void k_dense(const float* __restrict__ pooled,
    const float* __restrict__ dw, const float* __restrict__ db,
    float* __restrict__ out, int Gn) {
  int g = blockIdx.x * 256 + threadIdx.x;
  if (g < Gn) {
    float s = db[0];
    #pragma unroll
    for (int h = 0; h < HH2; ++h) s += pooled[(size_t)g * HH2 + h] * dw[h];
    out[g] = s;
  }
}

extern "C" void kernel_launch(void* const* d_in, const int* in_sizes, int n_in,
                              void* d_out, int out_size, void* d_ws, size_t ws_size,
                              hipStream_t stream) {
  const float* x     = (const float*)d_in[0];
  const int*   ei    = (const int*)d_in[1];
  const int*   ea    = (const int*)d_in[2];
  const int*   batch = (const int*)d_in[3];
  const float* W1    = (const float*)d_in[4];
  const float* root1 = (const float*)d_in[5];
  const float* b1    = (const float*)d_in[6];
  const float* W2    = (const float*)d_in[7];
  const float* root2 = (const float*)d_in[8];
  const float* b2    = (const float*)d_in[9];
  const float* dw    = (const float*)d_in[10];
  const float* db    = (const float*)d_in[11];
  float* out = (float*)d_out;

  const int N  = in_sizes[0] / FIN;
  const int E  = in_sizes[2];
  const int Gn = out_size;
  const int NB = (N + BNODES - 1) / BNODES;   // 391 for N=100000

  char* ws = (char*)d_ws;
  size_t off = 0;
  auto walloc = [&](size_t bytes) -> void* {
    void* p = (void*)(ws + off);
    off += (bytes + 255) & ~(size_t)255;
    return p;
  };
  int*            ghist   = (int*)            walloc((size_t)NBMAX * 4);
  int*            bbase   = (int*)            walloc(((size_t)NBMAX + 1) * 4);
  int*            gcursor = (int*)            walloc((size_t)NBMAX * 4);
  unsigned*       ebuf    = (unsigned*)       walloc((size_t)E * 4);
  __hip_bfloat16* xw1     = (__hip_bfloat16*) walloc((size_t)N * RNUM * HH1 * 2);
  float*          agg1    = (float*)          walloc((size_t)N * HH1 * 4);
  __hip_bfloat16* xw2     = (__hip_bfloat16*) walloc((size_t)N * RNUM * HH2 * 2);
  float*          agg2    = (float*)          walloc((size_t)N * HH2 * 4);
  unsigned*       pooled  = (unsigned*)       walloc((size_t)Gn * HH2 * 4);

  hipMemsetAsync(ghist, 0, (size_t)NBMAX * 4, stream);
  hipMemsetAsync(pooled, 0, (size_t)Gn * HH2 * 4, stream);

  k_bhist<<<(E + 4095) / 4096, 256, 0, stream>>>(ei, ghist, E, NB);
  k_bscan<<<1, NBMAX, 0, stream>>>(ghist, bbase, gcursor, NB, E);
  k_part<<<(E + PCHUNK - 1) / PCHUNK, 512, 0, stream>>>(ei, ea, gcursor, ebuf, E, NB);

  k_gemm1<<<(N + NPB - 1) / NPB, 256, 0, stream>>>(x, W1, root1, b1, xw1, agg1, N);
  k_agg1<<<NB, 512, 0, stream>>>(bbase, ebuf, xw1, agg1, N);
  k_gemm2<<<(N + NPB - 1) / NPB, 256, 0, stream>>>(agg1, W2, root2, b2, xw2, agg2, N);
  k_agg2<<<NB, 512, 0, stream>>>(bbase, ebuf, xw2, agg2, N);
  k_pool<<<(int)(((long)N * HH2 + 255) / 256), 256, 0, stream>>>(agg2, batch, pooled, N);
  k_dense<<<(Gn + 255) / 256, 256, 0, stream>>>((const float*)pooled, dw, db, out, Gn);
}

// Round 4
// 622.126 us; speedup vs baseline: 2.0798x; 2.0798x over previous
//
#include <hip/hip_runtime.h>
#include <hip/hip_bf16.h>

#define RNUM 8
#define HH1 32
#define HH2 16
#define FIN 128
#define NPB 16
#define BNODES 256      // nodes per bucket
#define NBMAX 512
#define PCHUNK 8192     // edges per partition block
#define SORTCAP 10240   // max edges per bucket the LDS sort handles
#define CAGG 128        // edges per (half/quarter)-wave in agg kernels

// --- bucket histogram (bucket = dst >> 8) ---
__global__ __launch_bounds__(256) void k_bhist(const int* __restrict__ ei,
    int* __restrict__ ghist, int E, int NB) {
  __shared__ int h[NBMAX];
  int t = threadIdx.x;
  for (int i = t; i < NBMAX; i += 256) h[i] = 0;
  __syncthreads();
  int base = blockIdx.x * 4096;
  #pragma unroll
  for (int j = 0; j < 16; ++j) {
    int e = base + j * 256 + t;
    if (e < E) atomicAdd(&h[ei[E + e] >> 8], 1);
  }
  __syncthreads();
  for (int i = t; i < NB; i += 256)
    if (h[i]) atomicAdd(&ghist[i], h[i]);
}

// --- exclusive scan of bucket counts -> bbase, init gcursor ---
__global__ __launch_bounds__(NBMAX) void k_bscan(const int* __restrict__ ghist,
    int* __restrict__ bbase, int* __restrict__ gcursor, int NB, int E) {
  __shared__ int buf[NBMAX];
  int t = threadIdx.x;
  int v = (t < NB) ? ghist[t] : 0;
  buf[t] = v;
  __syncthreads();
  for (int d = 1; d < NBMAX; d <<= 1) {
    int w = (t >= d) ? buf[t - d] : 0;
    __syncthreads();
    buf[t] += w;
    __syncthreads();
  }
  if (t < NB) {
    int ex = buf[t] - v;
    bbase[t] = ex;
    gcursor[t] = ex;
  }
  if (t == 0) bbase[NB] = E;
}

// --- partition edges into buckets with coalesced writes ---
__global__ __launch_bounds__(512) void k_part(const int* __restrict__ ei,
    const int* __restrict__ ea, int* __restrict__ gcursor,
    unsigned* __restrict__ ebuf, int E, int NB) {
  __shared__ unsigned reorder[PCHUNK];
  __shared__ unsigned short bkt[PCHUNK];
  __shared__ int hist[NBMAX], startl[NBMAX], cursor[NBMAX], gb[NBMAX], scanb[NBMAX];
  int t = threadIdx.x;
  int base = blockIdx.x * PCHUNK;
  int cn = min(PCHUNK, E - base);
  unsigned key[16];
  short bb[16];
  hist[t] = 0;
  __syncthreads();
  #pragma unroll
  for (int j = 0; j < 16; ++j) {
    int e = base + j * 512 + t;
    bb[j] = -1;
    if (e < E) {
      int src = ei[e], dst = ei[E + e], rel = ea[e];
      key[j] = ((unsigned)(dst & (BNODES - 1)) << 20) | ((unsigned)src << 3) | (unsigned)rel;
      int b = dst >> 8;
      bb[j] = (short)b;
      atomicAdd(&hist[b], 1);
    }
  }
  __syncthreads();
  int v = hist[t];
  scanb[t] = v;
  __syncthreads();
  for (int d = 1; d < NBMAX; d <<= 1) {
    int w = (t >= d) ? scanb[t - d] : 0;
    __syncthreads();
    scanb[t] += w;
    __syncthreads();
  }
  startl[t] = scanb[t] - v;
  cursor[t] = scanb[t] - v;
  __syncthreads();
  #pragma unroll
  for (int j = 0; j < 16; ++j) {
    if (bb[j] >= 0) {
      int pos = atomicAdd(&cursor[bb[j]], 1);
      reorder[pos] = key[j];
      bkt[pos] = (unsigned short)bb[j];
    }
  }
  __syncthreads();
  if (t < NB && hist[t] > 0) gb[t] = atomicAdd(&gcursor[t], hist[t]);
  __syncthreads();
  for (int p = t; p < cn; p += 512) {
    int b = bkt[p];
    ebuf[gb[b] + (p - startl[b])] = reorder[p];
  }
}

// --- per-bucket LDS counting sort by (dl,rel); emits invc; in-place on ebuf ---
__global__ __launch_bounds__(512) void k_sort(const int* __restrict__ bbase,
    unsigned* __restrict__ ebuf, float* __restrict__ invc, int NB) {
  __shared__ int hist[2048];
  __shared__ int part[512];
  __shared__ unsigned sorted[SORTCAP];
  int t = threadIdx.x;
  int b = blockIdx.x;
  int s = bbase[b], e = bbase[b + 1];
  int cn = e - s;
  for (int i = t; i < 2048; i += 512) hist[i] = 0;
  __syncthreads();
  for (int p = s + t; p < e; p += 512) {
    unsigned k = ebuf[p];
    atomicAdd(&hist[((k >> 20) << 3) | (k & 7u)], 1);
  }
  __syncthreads();
  // invc for this bucket's 256 nodes x 8 rels (global idx = ((b*256+dl)*8+rel))
  for (int i = t; i < 2048; i += 512) {
    int c = hist[i];
    invc[((size_t)b << 11) + i] = 1.0f / (float)(c > 1 ? c : 1);
  }
  // exclusive scan of hist[2048]
  int s0 = hist[4 * t], s1 = hist[4 * t + 1], s2 = hist[4 * t + 2], s3 = hist[4 * t + 3];
  int tot = s0 + s1 + s2 + s3;
  part[t] = tot;
  __syncthreads();
  for (int d = 1; d < 512; d <<= 1) {
    int v = (t >= d) ? part[t - d] : 0;
    __syncthreads();
    part[t] += v;
    __syncthreads();
  }
  int ex = part[t] - tot;
  __syncthreads();
  hist[4 * t] = ex;
  hist[4 * t + 1] = ex + s0;
  hist[4 * t + 2] = ex + s0 + s1;
  hist[4 * t + 3] = ex + s0 + s1 + s2;
  __syncthreads();
  if (cn <= SORTCAP) {
    for (int p = s + t; p < e; p += 512) {
      unsigned k = ebuf[p];
      int pos = atomicAdd(&hist[((k >> 20) << 3) | (k & 7u)], 1);
      sorted[pos] = k;
    }
    __syncthreads();
    for (int p = t; p < cn; p += 512) ebuf[s + p] = sorted[p];
  }
  // if cn > SORTCAP: leave unsorted — agg kernels remain correct (flush per change)
}

// xw1[n][r*32+h] (bf16) = x@W1 ; agg1[n][h] = x@root1 + b1
__global__ __launch_bounds__(256) void k_gemm1(const float* __restrict__ x,
    const float* __restrict__ W, const float* __restrict__ root,
    const float* __restrict__ b, __hip_bfloat16* __restrict__ xw,
    float* __restrict__ agg, int N) {
  __shared__ float xs[NPB][FIN];
  int n0 = blockIdx.x * NPB;
  int t = threadIdx.x;
  #pragma unroll
  for (int rep = 0; rep < 2; ++rep) {
    int q = t + rep * 256;
    int n = q >> 5;
    int i0 = (q & 31) << 2;
    int nn = n0 + n;
    float4 v = make_float4(0.f, 0.f, 0.f, 0.f);
    if (nn < N) v = *(const float4*)(x + (size_t)nn * FIN + i0);
    *(float4*)(&xs[n][i0]) = v;
  }
  __syncthreads();

  float acc[NPB];
  #pragma unroll
  for (int n = 0; n < NPB; ++n) acc[n] = 0.f;
  const float* Wc = W + ((t >> 5) * FIN * HH1) + (t & 31);
  #pragma unroll 4
  for (int i = 0; i < FIN; ++i) {
    float w = Wc[(size_t)i * HH1];
    #pragma unroll
    for (int n = 0; n < NPB; ++n) acc[n] = fmaf(w, xs[n][i], acc[n]);
  }
  #pragma unroll
  for (int n = 0; n < NPB; ++n) {
    int nn = n0 + n;
    if (nn < N) xw[(size_t)nn * (RNUM * HH1) + t] = __float2bfloat16(acc[n]);
  }

  int c = t & 31;
  int nr = t >> 5;
  float r0 = 0.f, r1 = 0.f;
  const float* Rc = root + c;
  #pragma unroll 4
  for (int i = 0; i < FIN; ++i) {
    float w = Rc[(size_t)i * HH1];
    r0 = fmaf(w, xs[nr][i], r0);
    r1 = fmaf(w, xs[nr + 8][i], r1);
  }
  float bb = b[c];
  int nn0 = n0 + nr, nn1 = n0 + nr + 8;
  if (nn0 < N) agg[(size_t)nn0 * HH1 + c] = r0 + bb;
  if (nn1 < N) agg[(size_t)nn1 * HH1 + c] = r1 + bb;
}

// sorted-run aggregation, layer 1: half-wave (32 lanes = h) per 128 edges
__global__ __launch_bounds__(256) void k_agg1(const int* __restrict__ bbase,
    const unsigned* __restrict__ ebuf, const float* __restrict__ invc,
    const __hip_bfloat16* __restrict__ xw, float* __restrict__ agg,
    int E, int NB) {
  long hw = (long)blockIdx.x * 8 + (threadIdx.x >> 5);
  int h = threadIdx.x & 31;
  long base = hw * CAGG;
  if (base >= E) return;
  int cnt = (int)((E - base < CAGG) ? (E - base) : CAGG);
  // binary search: largest b with bbase[b] <= base (bbase[NB]=E)
  int lo = 0, hi = NB;
  while (lo + 1 < hi) {
    int mid = (lo + hi) >> 1;
    if (bbase[mid] <= (int)base) lo = mid; else hi = mid;
  }
  int b = lo;
  int nb_end = bbase[b + 1];
  unsigned k = ebuf[base];
  int curdl = (int)(k >> 20);
  unsigned cursid = ((k >> 20) << 3) | (k & 7u);
  float w = invc[((size_t)b << 11) + cursid];
  float acc = 0.f;
  for (int j = 0; j < cnt; ++j) {
    long p = base + j;
    k = ebuf[p];
    if ((int)p >= nb_end) {
      atomicAdd(&agg[((size_t)((b << 8) + curdl) << 5) + h], acc);
      acc = 0.f;
      do { ++b; nb_end = bbase[b + 1]; } while (nb_end <= (int)p);
      curdl = (int)(k >> 20);
      cursid = ((k >> 20) << 3) | (k & 7u);
      w = invc[((size_t)b << 11) + cursid];
    } else {
      unsigned sid = ((k >> 20) << 3) | (k & 7u);
      if (sid != cursid) {
        int dl = (int)(k >> 20);
        if (dl != curdl) {
          atomicAdd(&agg[((size_t)((b << 8) + curdl) << 5) + h], acc);
          acc = 0.f;
          curdl = dl;
        }
        cursid = sid;
        w = invc[((size_t)b << 11) + sid];
      }
    }
    unsigned idx = k & 0xFFFFFu;
    acc = fmaf(w, __bfloat162float(xw[((size_t)idx << 5) + h]), acc);
  }
  atomicAdd(&agg[((size_t)((b << 8) + curdl) << 5) + h], acc);
}

// reads relu(agg1); xw2 (bf16) = h1@W2 ; agg2 = h1@root2 + b2
__global__ __launch_bounds__(256) void k_gemm2(const float* __restrict__ agg1,
    const float* __restrict__ W, const float* __restrict__ root,
    const float* __restrict__ b, __hip_bfloat16* __restrict__ xw,
    float* __restrict__ agg, int N) {
  __shared__ float hs[NPB][HH1];
  int n0 = blockIdx.x * NPB;
  int t = threadIdx.x;
  {
    int n = t >> 4;
    int i0 = (t & 15) << 1;
    int nn = n0 + n;
    float2 v = make_float2(0.f, 0.f);
    if (nn < N) v = *(const float2*)(agg1 + (size_t)nn * HH1 + i0);
    hs[n][i0] = fmaxf(v.x, 0.f);
    hs[n][i0 + 1] = fmaxf(v.y, 0.f);
  }
  __syncthreads();

  int c = t & 127;
  int ns = t >> 7;
  const float* Wc = W + ((c >> 4) * HH1 * HH2) + (c & 15);
  float acc[8];
  #pragma unroll
  for (int k = 0; k < 8; ++k) acc[k] = 0.f;
  #pragma unroll 4
  for (int i = 0; i < HH1; ++i) {
    float w = Wc[(size_t)i * HH2];
    #pragma unroll
    for (int k = 0; k < 8; ++k) acc[k] = fmaf(w, hs[ns + 2 * k][i], acc[k]);
  }
  #pragma unroll
  for (int k = 0; k < 8; ++k) {
    int nn = n0 + ns + 2 * k;
    if (nn < N) xw[(size_t)nn * (RNUM * HH2) + c] = __float2bfloat16(acc[k]);
  }

  int c2 = t & 15;
  int n = t >> 4;
  float r0 = 0.f;
  const float* Rc = root + c2;
  #pragma unroll 4
  for (int i = 0; i < HH1; ++i) r0 = fmaf(Rc[(size_t)i * HH2], hs[n][i], r0);
  int nn = n0 + n;
  if (nn < N) agg[(size_t)nn * HH2 + c2] = r0 + b[c2];
}

// sorted-run aggregation, layer 2: quarter-wave (16 lanes = h) per 128 edges
__global__ __launch_bounds__(256) void k_agg2(const int* __restrict__ bbase,
    const unsigned* __restrict__ ebuf, const float* __restrict__ invc,
    const __hip_bfloat16* __restrict__ xw, float* __restrict__ agg,
    int E, int NB) {
  long qw = (long)blockIdx.x * 16 + (threadIdx.x >> 4);
  int h = threadIdx.x & 15;
  long base = qw * CAGG;
  if (base >= E) return;
  int cnt = (int)((E - base < CAGG) ? (E - base) : CAGG);
  int lo = 0, hi = NB;
  while (lo + 1 < hi) {
    int mid = (lo + hi) >> 1;
    if (bbase[mid] <= (int)base) lo = mid; else hi = mid;
  }
  int b = lo;
  int nb_end = bbase[b + 1];
  unsigned k = ebuf[base];
  int curdl = (int)(k >> 20);
  unsigned cursid = ((k >> 20) << 3) | (k & 7u);
  float w = invc[((size_t)b << 11) + cursid];
  float acc = 0.f;
  for (int j = 0; j < cnt; ++j) {
    long p = base + j;
    k = ebuf[p];
    if ((int)p >= nb_end) {
      atomicAdd(&agg[((size_t)((b << 8) + curdl) << 4) + h], acc);
      acc = 0.f;
      do { ++b; nb_end = bbase[b + 1]; } while (nb_end <= (int)p);
      curdl = (int)(k >> 20);
      cursid = ((k >> 20) << 3) | (k & 7u);
      w = invc[((size_t)b << 11) + cursid];
    } else {
      unsigned sid = ((k >> 20) << 3) | (k & 7u);
      if (sid != cursid) {
        int dl = (int)(k >> 20);
        if (dl != curdl) {
          atomicAdd(&agg[((size_t)((b << 8) + curdl) << 4) + h], acc);
          acc = 0.f;
          curdl = dl;
        }
        cursid = sid;
        w = invc[((size_t)b << 11) + sid];
      }
    }
    unsigned idx = k & 0xFFFFFu;
    acc = fmaf(w, __bfloat162float(xw[((size_t)idx << 4) + h]), acc);
  }
  atomicAdd(&agg[((size_t)((b << 8) + curdl) << 4) + h], acc);
}

__global__ __launch_bounds__(256) void k_pool(const float* __restrict__ agg2,
    const int* __restrict__ batch, unsigned* __restrict__ pooled, int N) {
  int gid = blockIdx.x * 256 + threadIdx.x;
  int n = gid >> 4;
  if (n < N) {
    int h = gid & 15;
    float v = fmaxf(agg2[(size_t)n * HH2 + h], 0.f);
    atomicMax(&pooled[batch[n] * HH2 + h], __float_as_uint(v));
  }
}

__global__ __launch_bounds__(256) void k_dense(const float* __restrict__ pooled,
    const float* __restrict__ dw, const float* __restrict__ db,
    float* __restrict__ out, int Gn) {
  int g = blockIdx.x * 256 + threadIdx.x;
  if (g < Gn) {
    float s = db[0];
    #pragma unroll
    for (int h = 0; h < HH2; ++h) s += pooled[(size_t)g * HH2 + h] * dw[h];
    out[g] = s;
  }
}

extern "C" void kernel_launch(void* const* d_in, const int* in_sizes, int n_in,
                              void* d_out, int out_size, void* d_ws, size_t ws_size,
                              hipStream_t stream) {
  const float* x     = (const float*)d_in[0];
  const int*   ei    = (const int*)d_in[1];
  const int*   ea    = (const int*)d_in[2];
  const int*   batch = (const int*)d_in[3];
  const float* W1    = (const float*)d_in[4];
  const float* root1 = (const float*)d_in[5];
  const float* b1    = (const float*)d_in[6];
  const float* W2    = (const float*)d_in[7];
  const float* root2 = (const float*)d_in[8];
  const float* b2    = (const float*)d_in[9];
  const float* dw    = (const float*)d_in[10];
  const float* db    = (const float*)d_in[11];
  float* out = (float*)d_out;

  const int N  = in_sizes[0] / FIN;
  const int E  = in_sizes[2];
  const int Gn = out_size;
  const int NB = (N + BNODES - 1) / BNODES;   // 391 for N=100000

  char* ws = (char*)d_ws;
  size_t off = 0;
  auto walloc = [&](size_t bytes) -> void* {
    void* p = (void*)(ws + off);
    off += (bytes + 255) & ~(size_t)255;
    return p;
  };
  int*            ghist   = (int*)            walloc((size_t)NBMAX * 4);
  int*            bbase   = (int*)            walloc(((size_t)NBMAX + 1) * 4);
  int*            gcursor = (int*)            walloc((size_t)NBMAX * 4);
  unsigned*       ebuf    = (unsigned*)       walloc((size_t)E * 4);
  float*          invc    = (float*)          walloc((size_t)NB * 2048 * 4);
  __hip_bfloat16* xw1     = (__hip_bfloat16*) walloc((size_t)N * RNUM * HH1 * 2);
  float*          agg1    = (float*)          walloc((size_t)N * HH1 * 4);
  __hip_bfloat16* xw2     = (__hip_bfloat16*) walloc((size_t)N * RNUM * HH2 * 2);
  float*          agg2    = (float*)          walloc((size_t)N * HH2 * 4);
  unsigned*       pooled  = (unsigned*)       walloc((size_t)Gn * HH2 * 4);

  hipMemsetAsync(ghist, 0, (size_t)NBMAX * 4, stream);
  hipMemsetAsync(pooled, 0, (size_t)Gn * HH2 * 4, stream);

  k_bhist<<<(E + 4095) / 4096, 256, 0, stream>>>(ei, ghist, E, NB);
  k_bscan<<<1, NBMAX, 0, stream>>>(ghist, bbase, gcursor, NB, E);
  k_part<<<(E + PCHUNK - 1) / PCHUNK, 512, 0, stream>>>(ei, ea, gcursor, ebuf, E, NB);
  k_sort<<<NB, 512, 0, stream>>>(bbase, ebuf, invc, NB);

  k_gemm1<<<(N + NPB - 1) / NPB, 256, 0, stream>>>(x, W1, root1, b1, xw1, agg1, N);
  {
    long hw = ((long)E + CAGG - 1) / CAGG;
    k_agg1<<<(int)((hw + 7) / 8), 256, 0, stream>>>(bbase, ebuf, invc, xw1, agg1, E, NB);
  }
  k_gemm2<<<(N + NPB - 1) / NPB, 256, 0, stream>>>(agg1, W2, root2, b2, xw2, agg2, N);
  {
    long qw = ((long)E + CAGG - 1) / CAGG;
    k_agg2<<<(int)((qw + 15) / 16), 256, 0, stream>>>(bbase, ebuf, invc, xw2, agg2, E, NB);
  }
  k_pool<<<(int)(((long)N * HH2 + 255) / 256), 256, 0, stream>>>(agg2, batch, pooled, N);
  k_dense<<<(Gn + 255) / 256, 256, 0, stream>>>((const float*)pooled, dw, db, out, Gn);
}

// Round 5
// 466.551 us; speedup vs baseline: 2.7734x; 1.3335x over previous
//
#include <hip/hip_runtime.h>
#include <hip/hip_bf16.h>

#define RNUM 8
#define HH1 32
#define HH2 16
#define FIN 128
#define NPB 16
#define BNODES 256      // nodes per bucket
#define NBMAX 512
#define PCHUNK 8192     // edges per partition block
#define SORTCAP 10240   // max edges per bucket the LDS sort handles
#define CAGG 128        // edges per (half/quarter)-wave in agg kernels

// --- bucket histogram (bucket = dst >> 8) ---
__global__ __launch_bounds__(256) void k_bhist(const int* __restrict__ ei,
    int* __restrict__ ghist, int E, int NB) {
  __shared__ int h[NBMAX];
  int t = threadIdx.x;
  for (int i = t; i < NBMAX; i += 256) h[i] = 0;
  __syncthreads();
  int base = blockIdx.x * 4096;
  #pragma unroll
  for (int j = 0; j < 16; ++j) {
    int e = base + j * 256 + t;
    if (e < E) atomicAdd(&h[ei[E + e] >> 8], 1);
  }
  __syncthreads();
  for (int i = t; i < NB; i += 256)
    if (h[i]) atomicAdd(&ghist[i], h[i]);
}

// --- exclusive scan of bucket counts -> bbase, init gcursor ---
__global__ __launch_bounds__(NBMAX) void k_bscan(const int* __restrict__ ghist,
    int* __restrict__ bbase, int* __restrict__ gcursor, int NB, int E) {
  __shared__ int buf[NBMAX];
  int t = threadIdx.x;
  int v = (t < NB) ? ghist[t] : 0;
  buf[t] = v;
  __syncthreads();
  for (int d = 1; d < NBMAX; d <<= 1) {
    int w = (t >= d) ? buf[t - d] : 0;
    __syncthreads();
    buf[t] += w;
    __syncthreads();
  }
  if (t < NB) {
    int ex = buf[t] - v;
    bbase[t] = ex;
    gcursor[t] = ex;
  }
  if (t == 0) bbase[NB] = E;
}

// --- partition edges into buckets with coalesced writes ---
__global__ __launch_bounds__(512) void k_part(const int* __restrict__ ei,
    const int* __restrict__ ea, int* __restrict__ gcursor,
    unsigned* __restrict__ ebuf, int E, int NB) {
  __shared__ unsigned reorder[PCHUNK];
  __shared__ unsigned short bkt[PCHUNK];
  __shared__ int hist[NBMAX], startl[NBMAX], cursor[NBMAX], gb[NBMAX], scanb[NBMAX];
  int t = threadIdx.x;
  int base = blockIdx.x * PCHUNK;
  int cn = min(PCHUNK, E - base);
  unsigned key[16];
  short bb[16];
  hist[t] = 0;
  __syncthreads();
  #pragma unroll
  for (int j = 0; j < 16; ++j) {
    int e = base + j * 512 + t;
    bb[j] = -1;
    if (e < E) {
      int src = ei[e], dst = ei[E + e], rel = ea[e];
      key[j] = ((unsigned)(dst & (BNODES - 1)) << 20) | ((unsigned)src << 3) | (unsigned)rel;
      int b = dst >> 8;
      bb[j] = (short)b;
      atomicAdd(&hist[b], 1);
    }
  }
  __syncthreads();
  int v = hist[t];
  scanb[t] = v;
  __syncthreads();
  for (int d = 1; d < NBMAX; d <<= 1) {
    int w = (t >= d) ? scanb[t - d] : 0;
    __syncthreads();
    scanb[t] += w;
    __syncthreads();
  }
  startl[t] = scanb[t] - v;
  cursor[t] = scanb[t] - v;
  __syncthreads();
  #pragma unroll
  for (int j = 0; j < 16; ++j) {
    if (bb[j] >= 0) {
      int pos = atomicAdd(&cursor[bb[j]], 1);
      reorder[pos] = key[j];
      bkt[pos] = (unsigned short)bb[j];
    }
  }
  __syncthreads();
  if (t < NB && hist[t] > 0) gb[t] = atomicAdd(&gcursor[t], hist[t]);
  __syncthreads();
  for (int p = t; p < cn; p += 512) {
    int b = bkt[p];
    ebuf[gb[b] + (p - startl[b])] = reorder[p];
  }
}

// --- per-bucket LDS counting sort by (dl,rel); emits invc; in-place on ebuf ---
__global__ __launch_bounds__(512) void k_sort(const int* __restrict__ bbase,
    unsigned* __restrict__ ebuf, float* __restrict__ invc, int NB) {
  __shared__ int hist[2048];
  __shared__ int part[512];
  __shared__ unsigned sorted[SORTCAP];
  int t = threadIdx.x;
  int b = blockIdx.x;
  int s = bbase[b], e = bbase[b + 1];
  int cn = e - s;
  for (int i = t; i < 2048; i += 512) hist[i] = 0;
  __syncthreads();
  for (int p = s + t; p < e; p += 512) {
    unsigned k = ebuf[p];
    atomicAdd(&hist[((k >> 20) << 3) | (k & 7u)], 1);
  }
  __syncthreads();
  for (int i = t; i < 2048; i += 512) {
    int c = hist[i];
    invc[((size_t)b << 11) + i] = 1.0f / (float)(c > 1 ? c : 1);
  }
  int s0 = hist[4 * t], s1 = hist[4 * t + 1], s2 = hist[4 * t + 2], s3 = hist[4 * t + 3];
  int tot = s0 + s1 + s2 + s3;
  part[t] = tot;
  __syncthreads();
  for (int d = 1; d < 512; d <<= 1) {
    int v = (t >= d) ? part[t - d] : 0;
    __syncthreads();
    part[t] += v;
    __syncthreads();
  }
  int ex = part[t] - tot;
  __syncthreads();
  hist[4 * t] = ex;
  hist[4 * t + 1] = ex + s0;
  hist[4 * t + 2] = ex + s0 + s1;
  hist[4 * t + 3] = ex + s0 + s1 + s2;
  __syncthreads();
  if (cn <= SORTCAP) {
    for (int p = s + t; p < e; p += 512) {
      unsigned k = ebuf[p];
      int pos = atomicAdd(&hist[((k >> 20) << 3) | (k & 7u)], 1);
      sorted[pos] = k;
    }
    __syncthreads();
    for (int p = t; p < cn; p += 512) ebuf[s + p] = sorted[p];
  }
}

// xw1[n][r*32+h] (bf16) = x@W1 ; agg1[n][h] = x@root1 + b1
__global__ __launch_bounds__(256) void k_gemm1(const float* __restrict__ x,
    const float* __restrict__ W, const float* __restrict__ root,
    const float* __restrict__ b, __hip_bfloat16* __restrict__ xw,
    float* __restrict__ agg, int N) {
  __shared__ float xs[NPB][FIN];
  int n0 = blockIdx.x * NPB;
  int t = threadIdx.x;
  #pragma unroll
  for (int rep = 0; rep < 2; ++rep) {
    int q = t + rep * 256;
    int n = q >> 5;
    int i0 = (q & 31) << 2;
    int nn = n0 + n;
    float4 v = make_float4(0.f, 0.f, 0.f, 0.f);
    if (nn < N) v = *(const float4*)(x + (size_t)nn * FIN + i0);
    *(float4*)(&xs[n][i0]) = v;
  }
  __syncthreads();

  float acc[NPB];
  #pragma unroll
  for (int n = 0; n < NPB; ++n) acc[n] = 0.f;
  const float* Wc = W + ((t >> 5) * FIN * HH1) + (t & 31);
  #pragma unroll 4
  for (int i = 0; i < FIN; ++i) {
    float w = Wc[(size_t)i * HH1];
    #pragma unroll
    for (int n = 0; n < NPB; ++n) acc[n] = fmaf(w, xs[n][i], acc[n]);
  }
  #pragma unroll
  for (int n = 0; n < NPB; ++n) {
    int nn = n0 + n;
    if (nn < N) xw[(size_t)nn * (RNUM * HH1) + t] = __float2bfloat16(acc[n]);
  }

  int c = t & 31;
  int nr = t >> 5;
  float r0 = 0.f, r1 = 0.f;
  const float* Rc = root + c;
  #pragma unroll 4
  for (int i = 0; i < FIN; ++i) {
    float w = Rc[(size_t)i * HH1];
    r0 = fmaf(w, xs[nr][i], r0);
    r1 = fmaf(w, xs[nr + 8][i], r1);
  }
  float bb = b[c];
  int nn0 = n0 + nr, nn1 = n0 + nr + 8;
  if (nn0 < N) agg[(size_t)nn0 * HH1 + c] = r0 + bb;
  if (nn1 < N) agg[(size_t)nn1 * HH1 + c] = r1 + bb;
}

// sorted-run aggregation, layer 1: half-wave (32 lanes = h) per 128 edges,
// 8-deep gather batching for MLP
__global__ __launch_bounds__(256) void k_agg1(const int* __restrict__ bbase,
    const unsigned* __restrict__ ebuf, const float* __restrict__ invc,
    const __hip_bfloat16* __restrict__ xw, float* __restrict__ agg,
    int E, int NB, unsigned idxmax) {
  long hw = (long)blockIdx.x * 8 + (threadIdx.x >> 5);
  int h = threadIdx.x & 31;
  long base = hw * CAGG;
  if (base >= E) return;
  long rem = E - base;
  int cnt = (int)((rem < CAGG) ? rem : CAGG);
  int lo = 0, hi = NB;
  while (lo + 1 < hi) {
    int mid = (lo + hi) >> 1;
    if (bbase[mid] <= (int)base) lo = mid; else hi = mid;
  }
  int b = lo;
  int nb_end = bbase[b + 1];
  unsigned kf = ebuf[base];
  int curdl = (int)(kf >> 20);
  unsigned cursid = ((kf >> 20) << 3) | (kf & 7u);
  float w = invc[((size_t)b << 11) + cursid];
  float acc = 0.f;
  for (int j0 = 0; j0 < cnt; j0 += 8) {
    const unsigned* kp = ebuf + base + j0;
    uint4 ka = *(const uint4*)(kp);
    uint4 kb = *(const uint4*)(kp + 4);
    unsigned ks[8] = {ka.x, ka.y, ka.z, ka.w, kb.x, kb.y, kb.z, kb.w};
    float vs[8];
    #pragma unroll
    for (int u = 0; u < 8; ++u) {
      unsigned idx = ks[u] & 0xFFFFFu;
      idx = idx > idxmax ? idxmax : idx;
      vs[u] = __bfloat162float(xw[((size_t)idx << 5) + h]);
    }
    #pragma unroll
    for (int u = 0; u < 8; ++u) {
      int j = j0 + u;
      if (j >= cnt) break;
      long p = base + j;
      unsigned k = ks[u];
      if ((int)p >= nb_end) {
        atomicAdd(&agg[((size_t)((b << 8) + curdl) << 5) + h], acc);
        acc = 0.f;
        do { ++b; nb_end = bbase[b + 1]; } while (nb_end <= (int)p);
        curdl = (int)(k >> 20);
        cursid = ((k >> 20) << 3) | (k & 7u);
        w = invc[((size_t)b << 11) + cursid];
      } else {
        unsigned sid = ((k >> 20) << 3) | (k & 7u);
        if (sid != cursid) {
          int dl = (int)(k >> 20);
          if (dl != curdl) {
            atomicAdd(&agg[((size_t)((b << 8) + curdl) << 5) + h], acc);
            acc = 0.f;
            curdl = dl;
          }
          cursid = sid;
          w = invc[((size_t)b << 11) + sid];
        }
      }
      acc = fmaf(w, vs[u], acc);
    }
  }
  atomicAdd(&agg[((size_t)((b << 8) + curdl) << 5) + h], acc);
}

// reads relu(agg1); xw2 (bf16) = h1@W2 ; agg2 = h1@root2 + b2
__global__ __launch_bounds__(256) void k_gemm2(const float* __restrict__ agg1,
    const float* __restrict__ W, const float* __restrict__ root,
    const float* __restrict__ b, __hip_bfloat16* __restrict__ xw,
    float* __restrict__ agg, int N) {
  __shared__ float hs[NPB][HH1];
  int n0 = blockIdx.x * NPB;
  int t = threadIdx.x;
  {
    int n = t >> 4;
    int i0 = (t & 15) << 1;
    int nn = n0 + n;
    float2 v = make_float2(0.f, 0.f);
    if (nn < N) v = *(const float2*)(agg1 + (size_t)nn * HH1 + i0);
    hs[n][i0] = fmaxf(v.x, 0.f);
    hs[n][i0 + 1] = fmaxf(v.y, 0.f);
  }
  __syncthreads();

  int c = t & 127;
  int ns = t >> 7;
  const float* Wc = W + ((c >> 4) * HH1 * HH2) + (c & 15);
  float acc[8];
  #pragma unroll
  for (int k = 0; k < 8; ++k) acc[k] = 0.f;
  #pragma unroll 4
  for (int i = 0; i < HH1; ++i) {
    float w = Wc[(size_t)i * HH2];
    #pragma unroll
    for (int k = 0; k < 8; ++k) acc[k] = fmaf(w, hs[ns + 2 * k][i], acc[k]);
  }
  #pragma unroll
  for (int k = 0; k < 8; ++k) {
    int nn = n0 + ns + 2 * k;
    if (nn < N) xw[(size_t)nn * (RNUM * HH2) + c] = __float2bfloat16(acc[k]);
  }

  int c2 = t & 15;
  int n = t >> 4;
  float r0 = 0.f;
  const float* Rc = root + c2;
  #pragma unroll 4
  for (int i = 0; i < HH1; ++i) r0 = fmaf(Rc[(size_t)i * HH2], hs[n][i], r0);
  int nn = n0 + n;
  if (nn < N) agg[(size_t)nn * HH2 + c2] = r0 + b[c2];
}

// sorted-run aggregation, layer 2: quarter-wave (16 lanes = h) per 128 edges,
// 8-deep gather batching
__global__ __launch_bounds__(256) void k_agg2(const int* __restrict__ bbase,
    const unsigned* __restrict__ ebuf, const float* __restrict__ invc,
    const __hip_bfloat16* __restrict__ xw, float* __restrict__ agg,
    int E, int NB, unsigned idxmax) {
  long qw = (long)blockIdx.x * 16 + (threadIdx.x >> 4);
  int h = threadIdx.x & 15;
  long base = qw * CAGG;
  if (base >= E) return;
  long rem = E - base;
  int cnt = (int)((rem < CAGG) ? rem : CAGG);
  int lo = 0, hi = NB;
  while (lo + 1 < hi) {
    int mid = (lo + hi) >> 1;
    if (bbase[mid] <= (int)base) lo = mid; else hi = mid;
  }
  int b = lo;
  int nb_end = bbase[b + 1];
  unsigned kf = ebuf[base];
  int curdl = (int)(kf >> 20);
  unsigned cursid = ((kf >> 20) << 3) | (kf & 7u);
  float w = invc[((size_t)b << 11) + cursid];
  float acc = 0.f;
  for (int j0 = 0; j0 < cnt; j0 += 8) {
    const unsigned* kp = ebuf + base + j0;
    uint4 ka = *(const uint4*)(kp);
    uint4 kb = *(const uint4*)(kp + 4);
    unsigned ks[8] = {ka.x, ka.y, ka.z, ka.w, kb.x, kb.y, kb.z, kb.w};
    float vs[8];
    #pragma unroll
    for (int u = 0; u < 8; ++u) {
      unsigned idx = ks[u] & 0xFFFFFu;
      idx = idx > idxmax ? idxmax : idx;
      vs[u] = __bfloat162float(xw[((size_t)idx << 4) + h]);
    }
    #pragma unroll
    for (int u = 0; u < 8; ++u) {
      int j = j0 + u;
      if (j >= cnt) break;
      long p = base + j;
      unsigned k = ks[u];
      if ((int)p >= nb_end) {
        atomicAdd(&agg[((size_t)((b << 8) + curdl) << 4) + h], acc);
        acc = 0.f;
        do { ++b; nb_end = bbase[b + 1]; } while (nb_end <= (int)p);
        curdl = (int)(k >> 20);
        cursid = ((k >> 20) << 3) | (k & 7u);
        w = invc[((size_t)b << 11) + cursid];
      } else {
        unsigned sid = ((k >> 20) << 3) | (k & 7u);
        if (sid != cursid) {
          int dl = (int)(k >> 20);
          if (dl != curdl) {
            atomicAdd(&agg[((size_t)((b << 8) + curdl) << 4) + h], acc);
            acc = 0.f;
            curdl = dl;
          }
          cursid = sid;
          w = invc[((size_t)b << 11) + sid];
        }
      }
      acc = fmaf(w, vs[u], acc);
    }
  }
  atomicAdd(&agg[((size_t)((b << 8) + curdl) << 4) + h], acc);
}

__global__ __launch_bounds__(256) void k_pool(const float* __restrict__ agg2,
    const int* __restrict__ batch, unsigned* __restrict__ pooled, int N) {
  int gid = blockIdx.x * 256 + threadIdx.x;
  int n = gid >> 4;
  if (n < N) {
    int h = gid & 15;
    float v = fmaxf(agg2[(size_t)n * HH2 + h], 0.f);
    atomicMax(&pooled[batch[n] * HH2 + h], __float_as_uint(v));
  }
}

__global__ __launch_bounds__(256) void k_dense(const float* __restrict__ pooled,
    const float* __restrict__ dw, const float* __restrict__ db,
    float* __restrict__ out, int Gn) {
  int g = blockIdx.x * 256 + threadIdx.x;
  if (g < Gn) {
    float s = db[0];
    #pragma unroll
    for (int h = 0; h < HH2; ++h) s += pooled[(size_t)g * HH2 + h] * dw[h];
    out[g] = s;
  }
}

extern "C" void kernel_launch(void* const* d_in, const int* in_sizes, int n_in,
                              void* d_out, int out_size, void* d_ws, size_t ws_size,
                              hipStream_t stream) {
  const float* x     = (const float*)d_in[0];
  const int*   ei    = (const int*)d_in[1];
  const int*   ea    = (const int*)d_in[2];
  const int*   batch = (const int*)d_in[3];
  const float* W1    = (const float*)d_in[4];
  const float* root1 = (const float*)d_in[5];
  const float* b1    = (const float*)d_in[6];
  const float* W2    = (const float*)d_in[7];
  const float* root2 = (const float*)d_in[8];
  const float* b2    = (const float*)d_in[9];
  const float* dw    = (const float*)d_in[10];
  const float* db    = (const float*)d_in[11];
  float* out = (float*)d_out;

  const int N  = in_sizes[0] / FIN;
  const int E  = in_sizes[2];
  const int Gn = out_size;
  const int NB = (N + BNODES - 1) / BNODES;   // 391 for N=100000

  char* ws = (char*)d_ws;
  size_t off = 0;
  auto walloc = [&](size_t bytes) -> void* {
    void* p = (void*)(ws + off);
    off += (bytes + 255) & ~(size_t)255;
    return p;
  };
  int*            ghist   = (int*)            walloc((size_t)NBMAX * 4);
  int*            bbase   = (int*)            walloc(((size_t)NBMAX + 1) * 4);
  int*            gcursor = (int*)            walloc((size_t)NBMAX * 4);
  unsigned*       ebuf    = (unsigned*)       walloc((size_t)E * 4);
  float*          invc    = (float*)          walloc((size_t)NB * 2048 * 4);
  __hip_bfloat16* xw1     = (__hip_bfloat16*) walloc((size_t)N * RNUM * HH1 * 2);
  float*          agg1    = (float*)          walloc((size_t)N * HH1 * 4);
  __hip_bfloat16* xw2     = (__hip_bfloat16*) walloc((size_t)N * RNUM * HH2 * 2);
  float*          agg2    = (float*)          walloc((size_t)N * HH2 * 4);
  unsigned*       pooled  = (unsigned*)       walloc((size_t)Gn * HH2 * 4);

  hipMemsetAsync(ghist, 0, (size_t)NBMAX * 4, stream);
  hipMemsetAsync(pooled, 0, (size_t)Gn * HH2 * 4, stream);

  k_bhist<<<(E + 4095) / 4096, 256, 0, stream>>>(ei, ghist, E, NB);
  k_bscan<<<1, NBMAX, 0, stream>>>(ghist, bbase, gcursor, NB, E);
  k_part<<<(E + PCHUNK - 1) / PCHUNK, 512, 0, stream>>>(ei, ea, gcursor, ebuf, E, NB);
  k_sort<<<NB, 512, 0, stream>>>(bbase, ebuf, invc, NB);

  k_gemm1<<<(N + NPB - 1) / NPB, 256, 0, stream>>>(x, W1, root1, b1, xw1, agg1, N);
  {
    long hw = ((long)E + CAGG - 1) / CAGG;
    k_agg1<<<(int)((hw + 7) / 8), 256, 0, stream>>>(bbase, ebuf, invc, xw1, agg1, E, NB,
                                                    (unsigned)(N * RNUM - 1));
  }
  k_gemm2<<<(N + NPB - 1) / NPB, 256, 0, stream>>>(agg1, W2, root2, b2, xw2, agg2, N);
  {
    long qw = ((long)E + CAGG - 1) / CAGG;
    k_agg2<<<(int)((qw + 15) / 16), 256, 0, stream>>>(bbase, ebuf, invc, xw2, agg2, E, NB,
                                                      (unsigned)(N * RNUM - 1));
  }
  k_pool<<<(int)(((long)N * HH2 + 255) / 256), 256, 0, stream>>>(agg2, batch, pooled, N);
  k_dense<<<(Gn + 255) / 256, 256, 0, stream>>>((const float*)pooled, dw, db, out, Gn);
}

// Round 6
// 383.379 us; speedup vs baseline: 3.3750x; 1.2169x over previous
//
#include <hip/hip_runtime.h>
#include <hip/hip_bf16.h>

#define RNUM 8
#define HH1 32
#define HH2 16
#define FIN 128
#define NPB 16
#define BNODES 256      // nodes per bucket
#define NBMAX 512
#define PCHUNK 8192     // edges per partition block
#define SORTCAP 10240   // max edges per bucket the LDS sort handles
#define CAGG 128        // edges per (half/quarter)-wave in agg kernels

typedef short bf16x8 __attribute__((ext_vector_type(8)));
typedef float f32x4 __attribute__((ext_vector_type(4)));

__device__ inline bf16x8 cvt8(const float* __restrict__ p) {
  float tmp[8];
  *(float4*)tmp = *(const float4*)p;
  *(float4*)(tmp + 4) = *(const float4*)(p + 4);
  bf16x8 r;
  #pragma unroll
  for (int j = 0; j < 8; ++j) {
    union { __hip_bfloat16 h; short s; } cv;
    cv.h = __float2bfloat16(tmp[j]);
    r[j] = cv.s;
  }
  return r;
}

// --- bucket histogram (bucket = dst >> 8) ---
__global__ __launch_bounds__(256) void k_bhist(const int* __restrict__ ei,
    int* __restrict__ ghist, int E, int NB) {
  __shared__ int h[NBMAX];
  int t = threadIdx.x;
  for (int i = t; i < NBMAX; i += 256) h[i] = 0;
  __syncthreads();
  int base = blockIdx.x * 4096;
  #pragma unroll
  for (int j = 0; j < 16; ++j) {
    int e = base + j * 256 + t;
    if (e < E) atomicAdd(&h[ei[E + e] >> 8], 1);
  }
  __syncthreads();
  for (int i = t; i < NB; i += 256)
    if (h[i]) atomicAdd(&ghist[i], h[i]);
}

// --- exclusive scan of bucket counts -> bbase, init gcursor ---
__global__ __launch_bounds__(NBMAX) void k_bscan(const int* __restrict__ ghist,
    int* __restrict__ bbase, int* __restrict__ gcursor, int NB, int E) {
  __shared__ int buf[NBMAX];
  int t = threadIdx.x;
  int v = (t < NB) ? ghist[t] : 0;
  buf[t] = v;
  __syncthreads();
  for (int d = 1; d < NBMAX; d <<= 1) {
    int w = (t >= d) ? buf[t - d] : 0;
    __syncthreads();
    buf[t] += w;
    __syncthreads();
  }
  if (t < NB) {
    int ex = buf[t] - v;
    bbase[t] = ex;
    gcursor[t] = ex;
  }
  if (t == 0) bbase[NB] = E;
}

// --- partition edges into buckets with coalesced writes ---
__global__ __launch_bounds__(512) void k_part(const int* __restrict__ ei,
    const int* __restrict__ ea, int* __restrict__ gcursor,
    unsigned* __restrict__ ebuf, int E, int NB) {
  __shared__ unsigned reorder[PCHUNK];
  __shared__ unsigned short bkt[PCHUNK];
  __shared__ int hist[NBMAX], startl[NBMAX], cursor[NBMAX], gb[NBMAX], scanb[NBMAX];
  int t = threadIdx.x;
  int base = blockIdx.x * PCHUNK;
  int cn = min(PCHUNK, E - base);
  unsigned key[16];
  short bb[16];
  hist[t] = 0;
  __syncthreads();
  #pragma unroll
  for (int j = 0; j < 16; ++j) {
    int e = base + j * 512 + t;
    bb[j] = -1;
    if (e < E) {
      int src = ei[e], dst = ei[E + e], rel = ea[e];
      key[j] = ((unsigned)(dst & (BNODES - 1)) << 20) | ((unsigned)src << 3) | (unsigned)rel;
      int b = dst >> 8;
      bb[j] = (short)b;
      atomicAdd(&hist[b], 1);
    }
  }
  __syncthreads();
  int v = hist[t];
  scanb[t] = v;
  __syncthreads();
  for (int d = 1; d < NBMAX; d <<= 1) {
    int w = (t >= d) ? scanb[t - d] : 0;
    __syncthreads();
    scanb[t] += w;
    __syncthreads();
  }
  startl[t] = scanb[t] - v;
  cursor[t] = scanb[t] - v;
  __syncthreads();
  #pragma unroll
  for (int j = 0; j < 16; ++j) {
    if (bb[j] >= 0) {
      int pos = atomicAdd(&cursor[bb[j]], 1);
      reorder[pos] = key[j];
      bkt[pos] = (unsigned short)bb[j];
    }
  }
  __syncthreads();
  if (t < NB && hist[t] > 0) gb[t] = atomicAdd(&gcursor[t], hist[t]);
  __syncthreads();
  for (int p = t; p < cn; p += 512) {
    int b = bkt[p];
    ebuf[gb[b] + (p - startl[b])] = reorder[p];
  }
}

// --- per-bucket LDS counting sort by (dl,rel); emits invc; in-place on ebuf ---
__global__ __launch_bounds__(512) void k_sort(const int* __restrict__ bbase,
    unsigned* __restrict__ ebuf, float* __restrict__ invc, int NB) {
  __shared__ int hist[2048];
  __shared__ int part[512];
  __shared__ unsigned sorted[SORTCAP];
  int t = threadIdx.x;
  int b = blockIdx.x;
  int s = bbase[b], e = bbase[b + 1];
  int cn = e - s;
  for (int i = t; i < 2048; i += 512) hist[i] = 0;
  __syncthreads();
  for (int p = s + t; p < e; p += 512) {
    unsigned k = ebuf[p];
    atomicAdd(&hist[((k >> 20) << 3) | (k & 7u)], 1);
  }
  __syncthreads();
  for (int i = t; i < 2048; i += 512) {
    int c = hist[i];
    invc[((size_t)b << 11) + i] = 1.0f / (float)(c > 1 ? c : 1);
  }
  int s0 = hist[4 * t], s1 = hist[4 * t + 1], s2 = hist[4 * t + 2], s3 = hist[4 * t + 3];
  int tot = s0 + s1 + s2 + s3;
  part[t] = tot;
  __syncthreads();
  for (int d = 1; d < 512; d <<= 1) {
    int v = (t >= d) ? part[t - d] : 0;
    __syncthreads();
    part[t] += v;
    __syncthreads();
  }
  int ex = part[t] - tot;
  __syncthreads();
  hist[4 * t] = ex;
  hist[4 * t + 1] = ex + s0;
  hist[4 * t + 2] = ex + s0 + s1;
  hist[4 * t + 3] = ex + s0 + s1 + s2;
  __syncthreads();
  if (cn <= SORTCAP) {
    for (int p = s + t; p < e; p += 512) {
      unsigned k = ebuf[p];
      int pos = atomicAdd(&hist[((k >> 20) << 3) | (k & 7u)], 1);
      sorted[pos] = k;
    }
    __syncthreads();
    for (int p = t; p < cn; p += 512) ebuf[s + p] = sorted[p];
  }
}

// --- build Wcat bf16, col-major: Wcat[c][k], c<256: W1[c>>5][k][c&31]; c>=256: root1[k][c-256]
__global__ __launch_bounds__(256) void k_prepw(const float* __restrict__ W1,
    const float* __restrict__ root1, unsigned short* __restrict__ Wcat) {
  int id = blockIdx.x * 256 + threadIdx.x;
  if (id >= 288 * FIN) return;
  int c = id >> 7, k = id & 127;
  float v = (c < 256) ? W1[((size_t)(c >> 5) * FIN + k) * HH1 + (c & 31)]
                      : root1[(size_t)k * HH1 + (c - 256)];
  union { __hip_bfloat16 h; unsigned short u; } cv;
  cv.h = __float2bfloat16(v);
  Wcat[id] = cv.u;
}

// --- MFMA gemm1: per wave 32 rows x 288 cols; cols 0..255 -> xw1 bf16, 256..287 -> agg1+b1
__global__ __launch_bounds__(256) void k_gemm1m(const float* __restrict__ x,
    const unsigned short* __restrict__ Wcat, const float* __restrict__ b1,
    __hip_bfloat16* __restrict__ xw, float* __restrict__ agg, int N) {
  int lane = threadIdx.x & 63;
  int wv = threadIdx.x >> 6;
  int g = lane >> 4, lc = lane & 15;
  long nb = (long)blockIdx.x * 128 + wv * 32;
  f32x4 acc[2][18];
  #pragma unroll
  for (int m = 0; m < 2; ++m)
    #pragma unroll
    for (int j = 0; j < 18; ++j)
      acc[m][j] = (f32x4){0.f, 0.f, 0.f, 0.f};
  long rowA0 = nb + lc;       if (rowA0 > N - 1) rowA0 = N - 1;
  long rowA1 = nb + 16 + lc;  if (rowA1 > N - 1) rowA1 = N - 1;
  #pragma unroll
  for (int ks = 0; ks < 4; ++ks) {
    int ko = ks * 32 + g * 8;
    bf16x8 a0 = cvt8(x + rowA0 * FIN + ko);
    bf16x8 a1 = cvt8(x + rowA1 * FIN + ko);
    #pragma unroll
    for (int j = 0; j < 18; ++j) {
      bf16x8 bf = *(const bf16x8*)(Wcat + ((size_t)(16 * j + lc)) * FIN + ko);
      acc[0][j] = __builtin_amdgcn_mfma_f32_16x16x32_bf16(a0, bf, acc[0][j], 0, 0, 0);
      acc[1][j] = __builtin_amdgcn_mfma_f32_16x16x32_bf16(a1, bf, acc[1][j], 0, 0, 0);
    }
  }
  #pragma unroll
  for (int m = 0; m < 2; ++m) {
    #pragma unroll
    for (int j = 0; j < 18; ++j) {
      #pragma unroll
      for (int q = 0; q < 4; ++q) {
        long row = nb + 16 * m + g * 4 + q;
        if (row < N) {
          if (j < 16) {
            xw[row * 256 + 16 * j + lc] = __float2bfloat16(acc[m][j][q]);
          } else {
            int cc = (j - 16) * 16 + lc;
            agg[row * HH1 + cc] = acc[m][j][q] + b1[cc];
          }
        }
      }
    }
  }
}

// sorted-run aggregation, layer 1: half-wave (32 lanes = h) per 128 edges,
// 8-deep gather batching for MLP
__global__ __launch_bounds__(256) void k_agg1(const int* __restrict__ bbase,
    const unsigned* __restrict__ ebuf, const float* __restrict__ invc,
    const __hip_bfloat16* __restrict__ xw, float* __restrict__ agg,
    int E, int NB, unsigned idxmax) {
  long hw = (long)blockIdx.x * 8 + (threadIdx.x >> 5);
  int h = threadIdx.x & 31;
  long base = hw * CAGG;
  if (base >= E) return;
  long rem = E - base;
  int cnt = (int)((rem < CAGG) ? rem : CAGG);
  int lo = 0, hi = NB;
  while (lo + 1 < hi) {
    int mid = (lo + hi) >> 1;
    if (bbase[mid] <= (int)base) lo = mid; else hi = mid;
  }
  int b = lo;
  int nb_end = bbase[b + 1];
  unsigned kf = ebuf[base];
  int curdl = (int)(kf >> 20);
  unsigned cursid = ((kf >> 20) << 3) | (kf & 7u);
  float w = invc[((size_t)b << 11) + cursid];
  float acc = 0.f;
  for (int j0 = 0; j0 < cnt; j0 += 8) {
    const unsigned* kp = ebuf + base + j0;
    uint4 ka = *(const uint4*)(kp);
    uint4 kb = *(const uint4*)(kp + 4);
    unsigned ks[8] = {ka.x, ka.y, ka.z, ka.w, kb.x, kb.y, kb.z, kb.w};
    float vs[8];
    #pragma unroll
    for (int u = 0; u < 8; ++u) {
      unsigned idx = ks[u] & 0xFFFFFu;
      idx = idx > idxmax ? idxmax : idx;
      vs[u] = __bfloat162float(xw[((size_t)idx << 5) + h]);
    }
    #pragma unroll
    for (int u = 0; u < 8; ++u) {
      int j = j0 + u;
      if (j >= cnt) break;
      long p = base + j;
      unsigned k = ks[u];
      if ((int)p >= nb_end) {
        atomicAdd(&agg[((size_t)((b << 8) + curdl) << 5) + h], acc);
        acc = 0.f;
        do { ++b; nb_end = bbase[b + 1]; } while (nb_end <= (int)p);
        curdl = (int)(k >> 20);
        cursid = ((k >> 20) << 3) | (k & 7u);
        w = invc[((size_t)b << 11) + cursid];
      } else {
        unsigned sid = ((k >> 20) << 3) | (k & 7u);
        if (sid != cursid) {
          int dl = (int)(k >> 20);
          if (dl != curdl) {
            atomicAdd(&agg[((size_t)((b << 8) + curdl) << 5) + h], acc);
            acc = 0.f;
            curdl = dl;
          }
          cursid = sid;
          w = invc[((size_t)b << 11) + sid];
        }
      }
      acc = fmaf(w, vs[u], acc);
    }
  }
  atomicAdd(&agg[((size_t)((b << 8) + curdl) << 5) + h], acc);
}

// reads relu(agg1); xw2 (bf16) = h1@W2 ; agg2 = h1@root2 + b2
__global__ __launch_bounds__(256) void k_gemm2(const float* __restrict__ agg1,
    const float* __restrict__ W, const float* __restrict__ root,
    const float* __restrict__ b, __hip_bfloat16* __restrict__ xw,
    float* __restrict__ agg, int N) {
  __shared__ float hs[NPB][HH1];
  int n0 = blockIdx.x * NPB;
  int t = threadIdx.x;
  {
    int n = t >> 4;
    int i0 = (t & 15) << 1;
    int nn = n0 + n;
    float2 v = make_float2(0.f, 0.f);
    if (nn < N) v = *(const float2*)(agg1 + (size_t)nn * HH1 + i0);
    hs[n][i0] = fmaxf(v.x, 0.f);
    hs[n][i0 + 1] = fmaxf(v.y, 0.f);
  }
  __syncthreads();

  int c = t & 127;
  int ns = t >> 7;
  const float* Wc = W + ((c >> 4) * HH1 * HH2) + (c & 15);
  float acc[8];
  #pragma unroll
  for (int k = 0; k < 8; ++k) acc[k] = 0.f;
  #pragma unroll 4
  for (int i = 0; i < HH1; ++i) {
    float w = Wc[(size_t)i * HH2];
    #pragma unroll
    for (int k = 0; k < 8; ++k) acc[k] = fmaf(w, hs[ns + 2 * k][i], acc[k]);
  }
  #pragma unroll
  for (int k = 0; k < 8; ++k) {
    int nn = n0 + ns + 2 * k;
    if (nn < N) xw[(size_t)nn * (RNUM * HH2) + c] = __float2bfloat16(acc[k]);
  }

  int c2 = t & 15;
  int n = t >> 4;
  float r0 = 0.f;
  const float* Rc = root + c2;
  #pragma unroll 4
  for (int i = 0; i < HH1; ++i) r0 = fmaf(Rc[(size_t)i * HH2], hs[n][i], r0);
  int nn = n0 + n;
  if (nn < N) agg[(size_t)nn * HH2 + c2] = r0 + b[c2];
}

// sorted-run aggregation, layer 2: quarter-wave (16 lanes = h) per 128 edges,
// 8-deep gather batching
__global__ __launch_bounds__(256) void k_agg2(const int* __restrict__ bbase,
    const unsigned* __restrict__ ebuf, const float* __restrict__ invc,
    const __hip_bfloat16* __restrict__ xw, float* __restrict__ agg,
    int E, int NB, unsigned idxmax) {
  long qw = (long)blockIdx.x * 16 + (threadIdx.x >> 4);
  int h = threadIdx.x & 15;
  long base = qw * CAGG;
  if (base >= E) return;
  long rem = E - base;
  int cnt = (int)((rem < CAGG) ? rem : CAGG);
  int lo = 0, hi = NB;
  while (lo + 1 < hi) {
    int mid = (lo + hi) >> 1;
    if (bbase[mid] <= (int)base) lo = mid; else hi = mid;
  }
  int b = lo;
  int nb_end = bbase[b + 1];
  unsigned kf = ebuf[base];
  int curdl = (int)(kf >> 20);
  unsigned cursid = ((kf >> 20) << 3) | (kf & 7u);
  float w = invc[((size_t)b << 11) + cursid];
  float acc = 0.f;
  for (int j0 = 0; j0 < cnt; j0 += 8) {
    const unsigned* kp = ebuf + base + j0;
    uint4 ka = *(const uint4*)(kp);
    uint4 kb = *(const uint4*)(kp + 4);
    unsigned ks[8] = {ka.x, ka.y, ka.z, ka.w, kb.x, kb.y, kb.z, kb.w};
    float vs[8];
    #pragma unroll
    for (int u = 0; u < 8; ++u) {
      unsigned idx = ks[u] & 0xFFFFFu;
      idx = idx > idxmax ? idxmax : idx;
      vs[u] = __bfloat162float(xw[((size_t)idx << 4) + h]);
    }
    #pragma unroll
    for (int u = 0; u < 8; ++u) {
      int j = j0 + u;
      if (j >= cnt) break;
      long p = base + j;
      unsigned k = ks[u];
      if ((int)p >= nb_end) {
        atomicAdd(&agg[((size_t)((b << 8) + curdl) << 4) + h], acc);
        acc = 0.f;
        do { ++b; nb_end = bbase[b + 1]; } while (nb_end <= (int)p);
        curdl = (int)(k >> 20);
        cursid = ((k >> 20) << 3) | (k & 7u);
        w = invc[((size_t)b << 11) + cursid];
      } else {
        unsigned sid = ((k >> 20) << 3) | (k & 7u);
        if (sid != cursid) {
          int dl = (int)(k >> 20);
          if (dl != curdl) {
            atomicAdd(&agg[((size_t)((b << 8) + curdl) << 4) + h], acc);
            acc = 0.f;
            curdl = dl;
          }
          cursid = sid;
          w = invc[((size_t)b << 11) + sid];
        }
      }
      acc = fmaf(w, vs[u], acc);
    }
  }
  atomicAdd(&agg[((size_t)((b << 8) + curdl) << 4) + h], acc);
}

__global__ __launch_bounds__(256) void k_pool(const float* __restrict__ agg2,
    const int* __restrict__ batch, unsigned* __restrict__ pooled, int N) {
  int gid = blockIdx.x * 256 + threadIdx.x;
  int n = gid >> 4;
  if (n < N) {
    int h = gid & 15;
    float v = fmaxf(agg2[(size_t)n * HH2 + h], 0.f);
    atomicMax(&pooled[batch[n] * HH2 + h], __float_as_uint(v));
  }
}

__global__ __launch_bounds__(256) void k_dense(const float* __restrict__ pooled,
    const float* __restrict__ dw, const float* __restrict__ db,
    float* __restrict__ out, int Gn) {
  int g = blockIdx.x * 256 + threadIdx.x;
  if (g < Gn) {
    float s = db[0];
    #pragma unroll
    for (int h = 0; h < HH2; ++h) s += pooled[(size_t)g * HH2 + h] * dw[h];
    out[g] = s;
  }
}

extern "C" void kernel_launch(void* const* d_in, const int* in_sizes, int n_in,
                              void* d_out, int out_size, void* d_ws, size_t ws_size,
                              hipStream_t stream) {
  const float* x     = (const float*)d_in[0];
  const int*   ei    = (const int*)d_in[1];
  const int*   ea    = (const int*)d_in[2];
  const int*   batch = (const int*)d_in[3];
  const float* W1    = (const float*)d_in[4];
  const float* root1 = (const float*)d_in[5];
  const float* b1    = (const float*)d_in[6];
  const float* W2    = (const float*)d_in[7];
  const float* root2 = (const float*)d_in[8];
  const float* b2    = (const float*)d_in[9];
  const float* dw    = (const float*)d_in[10];
  const float* db    = (const float*)d_in[11];
  float* out = (float*)d_out;

  const int N  = in_sizes[0] / FIN;
  const int E  = in_sizes[2];
  const int Gn = out_size;
  const int NB = (N + BNODES - 1) / BNODES;   // 391 for N=100000

  char* ws = (char*)d_ws;
  size_t off = 0;
  auto walloc = [&](size_t bytes) -> void* {
    void* p = (void*)(ws + off);
    off += (bytes + 255) & ~(size_t)255;
    return p;
  };
  int*            ghist   = (int*)            walloc((size_t)NBMAX * 4);
  int*            bbase   = (int*)            walloc(((size_t)NBMAX + 1) * 4);
  int*            gcursor = (int*)            walloc((size_t)NBMAX * 4);
  unsigned*       ebuf    = (unsigned*)       walloc((size_t)E * 4);
  float*          invc    = (float*)          walloc((size_t)NB * 2048 * 4);
  unsigned short* Wcat    = (unsigned short*) walloc((size_t)288 * FIN * 2);
  __hip_bfloat16* xw1     = (__hip_bfloat16*) walloc((size_t)N * RNUM * HH1 * 2);
  float*          agg1    = (float*)          walloc((size_t)N * HH1 * 4);
  __hip_bfloat16* xw2     = (__hip_bfloat16*) walloc((size_t)N * RNUM * HH2 * 2);
  float*          agg2    = (float*)          walloc((size_t)N * HH2 * 4);
  unsigned*       pooled  = (unsigned*)       walloc((size_t)Gn * HH2 * 4);

  hipMemsetAsync(ghist, 0, (size_t)NBMAX * 4, stream);
  hipMemsetAsync(pooled, 0, (size_t)Gn * HH2 * 4, stream);

  k_prepw<<<(288 * FIN + 255) / 256, 256, 0, stream>>>(W1, root1, Wcat);
  k_bhist<<<(E + 4095) / 4096, 256, 0, stream>>>(ei, ghist, E, NB);
  k_bscan<<<1, NBMAX, 0, stream>>>(ghist, bbase, gcursor, NB, E);
  k_part<<<(E + PCHUNK - 1) / PCHUNK, 512, 0, stream>>>(ei, ea, gcursor, ebuf, E, NB);
  k_sort<<<NB, 512, 0, stream>>>(bbase, ebuf, invc, NB);

  k_gemm1m<<<(N + 127) / 128, 256, 0, stream>>>(x, Wcat, b1, xw1, agg1, N);
  {
    long hw = ((long)E + CAGG - 1) / CAGG;
    k_agg1<<<(int)((hw + 7) / 8), 256, 0, stream>>>(bbase, ebuf, invc, xw1, agg1, E, NB,
                                                    (unsigned)(N * RNUM - 1));
  }
  k_gemm2<<<(N + NPB - 1) / NPB, 256, 0, stream>>>(agg1, W2, root2, b2, xw2, agg2, N);
  {
    long qw = ((long)E + CAGG - 1) / CAGG;
    k_agg2<<<(int)((qw + 15) / 16), 256, 0, stream>>>(bbase, ebuf, invc, xw2, agg2, E, NB,
                                                      (unsigned)(N * RNUM - 1));
  }
  k_pool<<<(int)(((long)N * HH2 + 255) / 256), 256, 0, stream>>>(agg2, batch, pooled, N);
  k_dense<<<(Gn + 255) / 256, 256, 0, stream>>>((const float*)pooled, dw, db, out, Gn);
}

// Round 7
// 339.466 us; speedup vs baseline: 3.8116x; 1.1294x over previous
//
#include <hip/hip_runtime.h>
#include <hip/hip_bf16.h>

#define RNUM 8
#define HH1 32
#define HH2 16
#define FIN 128
#define NPB 16
#define BNODES 256      // nodes per bucket
#define NBMAX 512
#define PCHUNK 8192     // edges per partition block
#define SORTCAP 11264   // max PADDED edges per bucket the LDS sort handles

typedef short bf16x8 __attribute__((ext_vector_type(8)));
typedef float f32x4 __attribute__((ext_vector_type(4)));

__device__ inline bf16x8 cvt8(const float* __restrict__ p) {
  float tmp[8];
  *(float4*)tmp = *(const float4*)p;
  *(float4*)(tmp + 4) = *(const float4*)(p + 4);
  bf16x8 r;
  #pragma unroll
  for (int j = 0; j < 8; ++j) {
    union { __hip_bfloat16 h; short s; } cv;
    cv.h = __float2bfloat16(tmp[j]);
    r[j] = cv.s;
  }
  return r;
}

// --- bucket histogram (bucket = dst >> 8) ---
__global__ __launch_bounds__(256) void k_bhist(const int* __restrict__ ei,
    int* __restrict__ ghist, int E, int NB) {
  __shared__ int h[NBMAX];
  int t = threadIdx.x;
  for (int i = t; i < NBMAX; i += 256) h[i] = 0;
  __syncthreads();
  int base = blockIdx.x * 4096;
  #pragma unroll
  for (int j = 0; j < 16; ++j) {
    int e = base + j * 256 + t;
    if (e < E) atomicAdd(&h[ei[E + e] >> 8], 1);
  }
  __syncthreads();
  for (int i = t; i < NB; i += 256)
    if (h[i]) atomicAdd(&ghist[i], h[i]);
}

// --- exclusive scan of bucket counts -> bbase, init gcursor ---
__global__ __launch_bounds__(NBMAX) void k_bscan(const int* __restrict__ ghist,
    int* __restrict__ bbase, int* __restrict__ gcursor, int NB, int E) {
  __shared__ int buf[NBMAX];
  int t = threadIdx.x;
  int v = (t < NB) ? ghist[t] : 0;
  buf[t] = v;
  __syncthreads();
  for (int d = 1; d < NBMAX; d <<= 1) {
    int w = (t >= d) ? buf[t - d] : 0;
    __syncthreads();
    buf[t] += w;
    __syncthreads();
  }
  if (t < NB) {
    int ex = buf[t] - v;
    bbase[t] = ex;
    gcursor[t] = ex;
  }
  if (t == 0) bbase[NB] = E;
}

// --- partition edges into buckets with coalesced writes ---
__global__ __launch_bounds__(512) void k_part(const int* __restrict__ ei,
    const int* __restrict__ ea, int* __restrict__ gcursor,
    unsigned* __restrict__ ebuf, int E, int NB) {
  __shared__ unsigned reorder[PCHUNK];
  __shared__ unsigned short bkt[PCHUNK];
  __shared__ int hist[NBMAX], startl[NBMAX], cursor[NBMAX], gb[NBMAX], scanb[NBMAX];
  int t = threadIdx.x;
  int base = blockIdx.x * PCHUNK;
  int cn = min(PCHUNK, E - base);
  unsigned key[16];
  short bb[16];
  hist[t] = 0;
  __syncthreads();
  #pragma unroll
  for (int j = 0; j < 16; ++j) {
    int e = base + j * 512 + t;
    bb[j] = -1;
    if (e < E) {
      int src = ei[e], dst = ei[E + e], rel = ea[e];
      key[j] = ((unsigned)(dst & (BNODES - 1)) << 20) | ((unsigned)src << 3) | (unsigned)rel;
      int b = dst >> 8;
      bb[j] = (short)b;
      atomicAdd(&hist[b], 1);
    }
  }
  __syncthreads();
  int v = hist[t];
  scanb[t] = v;
  __syncthreads();
  for (int d = 1; d < NBMAX; d <<= 1) {
    int w = (t >= d) ? scanb[t - d] : 0;
    __syncthreads();
    scanb[t] += w;
    __syncthreads();
  }
  startl[t] = scanb[t] - v;
  cursor[t] = scanb[t] - v;
  __syncthreads();
  #pragma unroll
  for (int j = 0; j < 16; ++j) {
    if (bb[j] >= 0) {
      int pos = atomicAdd(&cursor[bb[j]], 1);
      reorder[pos] = key[j];
      bkt[pos] = (unsigned short)bb[j];
    }
  }
  __syncthreads();
  if (t < NB && hist[t] > 0) gb[t] = atomicAdd(&gcursor[t], hist[t]);
  __syncthreads();
  for (int p = t; p < cn; p += 512) {
    int b = bkt[p];
    ebuf[gb[b] + (p - startl[b])] = reorder[p];
  }
}

// --- per-bucket counting sort by (dl,rel) with per-dst 8-aligned padding ---
// emits: ebuf2 (sorted+padded keys), wbuf (per-edge weight, 0 on pads),
//        rps[dst] (padded start), rpc[dst] (real count)
__global__ __launch_bounds__(512) void k_sort(const int* __restrict__ bbase,
    const unsigned* __restrict__ ebuf, unsigned* __restrict__ ebuf2,
    float* __restrict__ wbuf, int* __restrict__ rps, int* __restrict__ rpc,
    int NB) {
  __shared__ int hist[2048];
  __shared__ float invw[2048];
  __shared__ int dlc[256];
  __shared__ unsigned sorted[SORTCAP];
  int t = threadIdx.x;
  int b = blockIdx.x;
  int s = bbase[b], e = bbase[b + 1];
  int out_s = ((s + 7) & ~7) + (b << 11);   // 8-aligned bucket base with pad slack
  for (int i = t; i < 2048; i += 512) hist[i] = 0;
  __syncthreads();
  for (int p = s + t; p < e; p += 512) {
    unsigned k = ebuf[p];
    atomicAdd(&hist[((k >> 20) << 3) | (k & 7u)], 1);
  }
  __syncthreads();
  for (int i = t; i < 2048; i += 512) {
    int c = hist[i];
    invw[i] = 1.0f / (float)(c > 1 ? c : 1);
  }
  __syncthreads();
  // per-dl serial prefix over 8 rel bins; padded count per dl
  int pr[8];
  int cdl = 0, pc = 0;
  if (t < 256) {
    #pragma unroll
    for (int r = 0; r < 8; ++r) { pr[r] = cdl; cdl += hist[8 * t + r]; }
    pc = (cdl + 7) & ~7;
    dlc[t] = pc;
  }
  __syncthreads();
  // inclusive scan of dlc[256]
  for (int d = 1; d < 256; d <<= 1) {
    int w = (t < 256 && t >= d) ? dlc[t - d] : 0;
    __syncthreads();
    if (t < 256) dlc[t] += w;
    __syncthreads();
  }
  if (t < 256) {
    int ebase = dlc[t] - pc;
    #pragma unroll
    for (int r = 0; r < 8; ++r) hist[8 * t + r] = ebase + pr[r];  // bin cursors
    rps[(b << 8) + t] = out_s + ebase;
    rpc[(b << 8) + t] = cdl;
  }
  __syncthreads();
  int ptot = dlc[255];
  if (ptot <= SORTCAP) {
    for (int p = t; p < ptot; p += 512) sorted[p] = 0xFFFFFFFFu;
    __syncthreads();
    for (int p = s + t; p < e; p += 512) {
      unsigned k = ebuf[p];
      int pos = atomicAdd(&hist[((k >> 20) << 3) | (k & 7u)], 1);
      sorted[pos] = k;
    }
    __syncthreads();
    for (int p = t; p < ptot; p += 512) {
      unsigned k = sorted[p];
      int o = out_s + p;
      if (k == 0xFFFFFFFFu) { ebuf2[o] = 0u; wbuf[o] = 0.f; }
      else { ebuf2[o] = k; wbuf[o] = invw[((k >> 20) << 3) | (k & 7u)]; }
    }
  } else {
    // correctness fallback (never triggered at this edge distribution)
    if (t < 256) {
      int ebase = dlc[t] - pc;
      for (int p = ebase + cdl; p < dlc[t]; ++p) {
        ebuf2[out_s + p] = 0u; wbuf[out_s + p] = 0.f;
      }
    }
    __syncthreads();
    for (int p = s + t; p < e; p += 512) {
      unsigned k = ebuf[p];
      int bin = ((k >> 20) << 3) | (k & 7u);
      int pos = atomicAdd(&hist[bin], 1);
      ebuf2[out_s + pos] = k;
      wbuf[out_s + pos] = invw[bin];
    }
  }
}

// --- build Wcat bf16, col-major: Wcat[c][k], c<256: W1[c>>5][k][c&31]; c>=256: root1[k][c-256]
__global__ __launch_bounds__(256) void k_prepw(const float* __restrict__ W1,
    const float* __restrict__ root1, unsigned short* __restrict__ Wcat) {
  int id = blockIdx.x * 256 + threadIdx.x;
  if (id >= 288 * FIN) return;
  int c = id >> 7, k = id & 127;
  float v = (c < 256) ? W1[((size_t)(c >> 5) * FIN + k) * HH1 + (c & 31)]
                      : root1[(size_t)k * HH1 + (c - 256)];
  union { __hip_bfloat16 h; unsigned short u; } cv;
  cv.h = __float2bfloat16(v);
  Wcat[id] = cv.u;
}

// --- MFMA gemm1: per wave 32 rows x 288 cols; cols 0..255 -> xw1 bf16, 256..287 -> agg1+b1
__global__ __launch_bounds__(256) void k_gemm1m(const float* __restrict__ x,
    const unsigned short* __restrict__ Wcat, const float* __restrict__ b1,
    __hip_bfloat16* __restrict__ xw, float* __restrict__ agg, int N) {
  int lane = threadIdx.x & 63;
  int wv = threadIdx.x >> 6;
  int g = lane >> 4, lc = lane & 15;
  long nb = (long)blockIdx.x * 128 + wv * 32;
  f32x4 acc[2][18];
  #pragma unroll
  for (int m = 0; m < 2; ++m)
    #pragma unroll
    for (int j = 0; j < 18; ++j)
      acc[m][j] = (f32x4){0.f, 0.f, 0.f, 0.f};
  long rowA0 = nb + lc;       if (rowA0 > N - 1) rowA0 = N - 1;
  long rowA1 = nb + 16 + lc;  if (rowA1 > N - 1) rowA1 = N - 1;
  #pragma unroll
  for (int ks = 0; ks < 4; ++ks) {
    int ko = ks * 32 + g * 8;
    bf16x8 a0 = cvt8(x + rowA0 * FIN + ko);
    bf16x8 a1 = cvt8(x + rowA1 * FIN + ko);
    #pragma unroll
    for (int j = 0; j < 18; ++j) {
      bf16x8 bf = *(const bf16x8*)(Wcat + ((size_t)(16 * j + lc)) * FIN + ko);
      acc[0][j] = __builtin_amdgcn_mfma_f32_16x16x32_bf16(a0, bf, acc[0][j], 0, 0, 0);
      acc[1][j] = __builtin_amdgcn_mfma_f32_16x16x32_bf16(a1, bf, acc[1][j], 0, 0, 0);
    }
  }
  #pragma unroll
  for (int m = 0; m < 2; ++m) {
    #pragma unroll
    for (int j = 0; j < 18; ++j) {
      #pragma unroll
      for (int q = 0; q < 4; ++q) {
        long row = nb + 16 * m + g * 4 + q;
        if (row < N) {
          if (j < 16) {
            xw[row * 256 + 16 * j + lc] = __float2bfloat16(acc[m][j][q]);
          } else {
            int cc = (j - 16) * 16 + lc;
            agg[row * HH1 + cc] = acc[m][j][q] + b1[cc];
          }
        }
      }
    }
  }
}

// layer-1 aggregation: one wave64 per dst; 32 h-lanes x 2 edge-substreams;
// branch-free 8-deep batches over padded sorted segment; non-atomic output
__global__ __launch_bounds__(256) void k_agg1(const int* __restrict__ rps,
    const int* __restrict__ rpc, const unsigned* __restrict__ eb,
    const float* __restrict__ wb, const __hip_bfloat16* __restrict__ xw,
    float* __restrict__ agg, int N) {
  int d = blockIdx.x * 4 + (threadIdx.x >> 6);
  if (d >= N) return;
  int lane = threadIdx.x & 63;
  int h = lane & 31, half = lane >> 5;
  int s = rps[d];
  int cnt = rpc[d];
  float acc = 0.f;
  for (int j = half * 8; j < cnt; j += 16) {
    const unsigned* kp = eb + s + j;
    uint4 ka = *(const uint4*)kp;
    uint4 kb = *(const uint4*)(kp + 4);
    float4 wa = *(const float4*)(wb + s + j);
    float4 wc = *(const float4*)(wb + s + j + 4);
    unsigned ks[8] = {ka.x, ka.y, ka.z, ka.w, kb.x, kb.y, kb.z, kb.w};
    float ws[8] = {wa.x, wa.y, wa.z, wa.w, wc.x, wc.y, wc.z, wc.w};
    #pragma unroll
    for (int u = 0; u < 8; ++u) {
      unsigned idx = ks[u] & 0xFFFFFu;
      float v = __bfloat162float(xw[((size_t)idx << 5) + h]);
      acc = fmaf(ws[u], v, acc);
    }
  }
  acc += __shfl_xor(acc, 32);
  if (half == 0) agg[((size_t)d << 5) + h] += acc;
}

// reads relu(agg1); xw2 (bf16) = h1@W2 ; agg2 = h1@root2 + b2
__global__ __launch_bounds__(256) void k_gemm2(const float* __restrict__ agg1,
    const float* __restrict__ W, const float* __restrict__ root,
    const float* __restrict__ b, __hip_bfloat16* __restrict__ xw,
    float* __restrict__ agg, int N) {
  __shared__ float hs[NPB][HH1];
  int n0 = blockIdx.x * NPB;
  int t = threadIdx.x;
  {
    int n = t >> 4;
    int i0 = (t & 15) << 1;
    int nn = n0 + n;
    float2 v = make_float2(0.f, 0.f);
    if (nn < N) v = *(const float2*)(agg1 + (size_t)nn * HH1 + i0);
    hs[n][i0] = fmaxf(v.x, 0.f);
    hs[n][i0 + 1] = fmaxf(v.y, 0.f);
  }
  __syncthreads();

  int c = t & 127;
  int ns = t >> 7;
  const float* Wc = W + ((c >> 4) * HH1 * HH2) + (c & 15);
  float acc[8];
  #pragma unroll
  for (int k = 0; k < 8; ++k) acc[k] = 0.f;
  #pragma unroll 4
  for (int i = 0; i < HH1; ++i) {
    float w = Wc[(size_t)i * HH2];
    #pragma unroll
    for (int k = 0; k < 8; ++k) acc[k] = fmaf(w, hs[ns + 2 * k][i], acc[k]);
  }
  #pragma unroll
  for (int k = 0; k < 8; ++k) {
    int nn = n0 + ns + 2 * k;
    if (nn < N) xw[(size_t)nn * (RNUM * HH2) + c] = __float2bfloat16(acc[k]);
  }

  int c2 = t & 15;
  int n = t >> 4;
  float r0 = 0.f;
  const float* Rc = root + c2;
  #pragma unroll 4
  for (int i = 0; i < HH1; ++i) r0 = fmaf(Rc[(size_t)i * HH2], hs[n][i], r0);
  int nn = n0 + n;
  if (nn < N) agg[(size_t)nn * HH2 + c2] = r0 + b[c2];
}

// layer-2 aggregation: one wave64 per dst; 16 h-lanes x 4 edge-substreams
__global__ __launch_bounds__(256) void k_agg2(const int* __restrict__ rps,
    const int* __restrict__ rpc, const unsigned* __restrict__ eb,
    const float* __restrict__ wb, const __hip_bfloat16* __restrict__ xw,
    float* __restrict__ agg, int N) {
  int d = blockIdx.x * 4 + (threadIdx.x >> 6);
  if (d >= N) return;
  int lane = threadIdx.x & 63;
  int h = lane & 15, q = lane >> 4;
  int s = rps[d];
  int cnt = rpc[d];
  float acc = 0.f;
  for (int j = q * 8; j < cnt; j += 32) {
    const unsigned* kp = eb + s + j;
    uint4 ka = *(const uint4*)kp;
    uint4 kb = *(const uint4*)(kp + 4);
    float4 wa = *(const float4*)(wb + s + j);
    float4 wc = *(const float4*)(wb + s + j + 4);
    unsigned ks[8] = {ka.x, ka.y, ka.z, ka.w, kb.x, kb.y, kb.z, kb.w};
    float ws[8] = {wa.x, wa.y, wa.z, wa.w, wc.x, wc.y, wc.z, wc.w};
    #pragma unroll
    for (int u = 0; u < 8; ++u) {
      unsigned idx = ks[u] & 0xFFFFFu;
      float v = __bfloat162float(xw[((size_t)idx << 4) + h]);
      acc = fmaf(ws[u], v, acc);
    }
  }
  acc += __shfl_xor(acc, 32);
  acc += __shfl_xor(acc, 16);
  if (q == 0) agg[((size_t)d << 4) + h] += acc;
}

__global__ __launch_bounds__(256) void k_pool(const float* __restrict__ agg2,
    const int* __restrict__ batch, unsigned* __restrict__ pooled, int N) {
  int gid = blockIdx.x * 256 + threadIdx.x;
  int n = gid >> 4;
  if (n < N) {
    int h = gid & 15;
    float v = fmaxf(agg2[(size_t)n * HH2 + h], 0.f);
    atomicMax(&pooled[batch[n] * HH2 + h], __float_as_uint(v));
  }
}

__global__ __launch_bounds__(256) void k_dense(const float* __restrict__ pooled,
    const float* __restrict__ dw, const float* __restrict__ db,
    float* __restrict__ out, int Gn) {
  int g = blockIdx.x * 256 + threadIdx.x;
  if (g < Gn) {
    float s = db[0];
    #pragma unroll
    for (int h = 0; h < HH2; ++h) s += pooled[(size_t)g * HH2 + h] * dw[h];
    out[g] = s;
  }
}

extern "C" void kernel_launch(void* const* d_in, const int* in_sizes, int n_in,
                              void* d_out, int out_size, void* d_ws, size_t ws_size,
                              hipStream_t stream) {
  const float* x     = (const float*)d_in[0];
  const int*   ei    = (const int*)d_in[1];
  const int*   ea    = (const int*)d_in[2];
  const int*   batch = (const int*)d_in[3];
  const float* W1    = (const float*)d_in[4];
  const float* root1 = (const float*)d_in[5];
  const float* b1    = (const float*)d_in[6];
  const float* W2    = (const float*)d_in[7];
  const float* root2 = (const float*)d_in[8];
  const float* b2    = (const float*)d_in[9];
  const float* dw    = (const float*)d_in[10];
  const float* db    = (const float*)d_in[11];
  float* out = (float*)d_out;

  const int N  = in_sizes[0] / FIN;
  const int E  = in_sizes[2];
  const int Gn = out_size;
  const int NB = (N + BNODES - 1) / BNODES;   // 391 for N=100000

  char* ws = (char*)d_ws;
  size_t off = 0;
  auto walloc = [&](size_t bytes) -> void* {
    void* p = (void*)(ws + off);
    off += (bytes + 255) & ~(size_t)255;
    return p;
  };
  const size_t EP = (size_t)E + (size_t)NBMAX * 2048 + 64;  // padded edge capacity
  int*            ghist   = (int*)            walloc((size_t)NBMAX * 4);
  int*            bbase   = (int*)            walloc(((size_t)NBMAX + 1) * 4);
  int*            gcursor = (int*)            walloc((size_t)NBMAX * 4);
  unsigned*       ebuf    = (unsigned*)       walloc((size_t)E * 4);
  unsigned*       ebuf2   = (unsigned*)       walloc(EP * 4);
  float*          wbuf    = (float*)          walloc(EP * 4);
  int*            rps     = (int*)            walloc((size_t)NBMAX * 256 * 4);
  int*            rpc     = (int*)            walloc((size_t)NBMAX * 256 * 4);
  unsigned short* Wcat    = (unsigned short*) walloc((size_t)288 * FIN * 2);
  __hip_bfloat16* xw1     = (__hip_bfloat16*) walloc((size_t)N * RNUM * HH1 * 2);
  float*          agg1    = (float*)          walloc((size_t)N * HH1 * 4);
  __hip_bfloat16* xw2     = (__hip_bfloat16*) walloc((size_t)N * RNUM * HH2 * 2);
  float*          agg2    = (float*)          walloc((size_t)N * HH2 * 4);
  unsigned*       pooled  = (unsigned*)       walloc((size_t)Gn * HH2 * 4);

  hipMemsetAsync(ghist, 0, (size_t)NBMAX * 4, stream);
  hipMemsetAsync(pooled, 0, (size_t)Gn * HH2 * 4, stream);

  k_prepw<<<(288 * FIN + 255) / 256, 256, 0, stream>>>(W1, root1, Wcat);
  k_bhist<<<(E + 4095) / 4096, 256, 0, stream>>>(ei, ghist, E, NB);
  k_bscan<<<1, NBMAX, 0, stream>>>(ghist, bbase, gcursor, NB, E);
  k_part<<<(E + PCHUNK - 1) / PCHUNK, 512, 0, stream>>>(ei, ea, gcursor, ebuf, E, NB);
  k_sort<<<NB, 512, 0, stream>>>(bbase, ebuf, ebuf2, wbuf, rps, rpc, NB);

  k_gemm1m<<<(N + 127) / 128, 256, 0, stream>>>(x, Wcat, b1, xw1, agg1, N);
  k_agg1<<<(N + 3) / 4, 256, 0, stream>>>(rps, rpc, ebuf2, wbuf, xw1, agg1, N);
  k_gemm2<<<(N + NPB - 1) / NPB, 256, 0, stream>>>(agg1, W2, root2, b2, xw2, agg2, N);
  k_agg2<<<(N + 3) / 4, 256, 0, stream>>>(rps, rpc, ebuf2, wbuf, xw2, agg2, N);
  k_pool<<<(int)(((long)N * HH2 + 255) / 256), 256, 0, stream>>>(agg2, batch, pooled, N);
  k_dense<<<(Gn + 255) / 256, 256, 0, stream>>>((const float*)pooled, dw, db, out, Gn);
}

// Round 8
// 286.432 us; speedup vs baseline: 4.5173x; 1.1852x over previous
//
#include <hip/hip_runtime.h>
#include <hip/hip_bf16.h>

#define RNUM 8
#define HH1 32
#define HH2 16
#define FIN 128
#define BNODES 256      // nodes per bucket
#define NBMAX 512
#define PCHUNK 8192     // edges per partition block
#define SORTCAP 11264   // max PADDED edges per bucket the LDS sort handles

#define W1STR 136       // padded col stride (shorts) for Wcat  [288][136]
#define W1ELTS (288 * W1STR)
#define W2STR 40        // padded col stride (shorts) for W2cat [144][40]
#define W2ELTS (144 * W2STR)

typedef short bf16x8 __attribute__((ext_vector_type(8)));
typedef float f32x4 __attribute__((ext_vector_type(4)));

__device__ inline bf16x8 cvt8(const float* __restrict__ p) {
  float tmp[8];
  *(float4*)tmp = *(const float4*)p;
  *(float4*)(tmp + 4) = *(const float4*)(p + 4);
  bf16x8 r;
  #pragma unroll
  for (int j = 0; j < 8; ++j) {
    union { __hip_bfloat16 h; short s; } cv;
    cv.h = __float2bfloat16(tmp[j]);
    r[j] = cv.s;
  }
  return r;
}

__device__ inline bf16x8 cvt8relu(const float* __restrict__ p) {
  float tmp[8];
  *(float4*)tmp = *(const float4*)p;
  *(float4*)(tmp + 4) = *(const float4*)(p + 4);
  bf16x8 r;
  #pragma unroll
  for (int j = 0; j < 8; ++j) {
    union { __hip_bfloat16 h; short s; } cv;
    cv.h = __float2bfloat16(fmaxf(tmp[j], 0.f));
    r[j] = cv.s;
  }
  return r;
}

// --- bucket histogram (bucket = dst >> 8) ---
__global__ __launch_bounds__(256) void k_bhist(const int* __restrict__ ei,
    int* __restrict__ ghist, int E, int NB) {
  __shared__ int h[NBMAX];
  int t = threadIdx.x;
  for (int i = t; i < NBMAX; i += 256) h[i] = 0;
  __syncthreads();
  int base = blockIdx.x * 4096;
  #pragma unroll
  for (int j = 0; j < 16; ++j) {
    int e = base + j * 256 + t;
    if (e < E) atomicAdd(&h[ei[E + e] >> 8], 1);
  }
  __syncthreads();
  for (int i = t; i < NB; i += 256)
    if (h[i]) atomicAdd(&ghist[i], h[i]);
}

// --- exclusive scan of bucket counts -> bbase, init gcursor ---
__global__ __launch_bounds__(NBMAX) void k_bscan(const int* __restrict__ ghist,
    int* __restrict__ bbase, int* __restrict__ gcursor, int NB, int E) {
  __shared__ int buf[NBMAX];
  int t = threadIdx.x;
  int v = (t < NB) ? ghist[t] : 0;
  buf[t] = v;
  __syncthreads();
  for (int d = 1; d < NBMAX; d <<= 1) {
    int w = (t >= d) ? buf[t - d] : 0;
    __syncthreads();
    buf[t] += w;
    __syncthreads();
  }
  if (t < NB) {
    int ex = buf[t] - v;
    bbase[t] = ex;
    gcursor[t] = ex;
  }
  if (t == 0) bbase[NB] = E;
}

// --- partition edges into buckets with coalesced writes ---
__global__ __launch_bounds__(512) void k_part(const int* __restrict__ ei,
    const int* __restrict__ ea, int* __restrict__ gcursor,
    unsigned* __restrict__ ebuf, int E, int NB) {
  __shared__ unsigned reorder[PCHUNK];
  __shared__ unsigned short bkt[PCHUNK];
  __shared__ int hist[NBMAX], startl[NBMAX], cursor[NBMAX], gb[NBMAX], scanb[NBMAX];
  int t = threadIdx.x;
  int base = blockIdx.x * PCHUNK;
  int cn = min(PCHUNK, E - base);
  unsigned key[16];
  short bb[16];
  hist[t] = 0;
  __syncthreads();
  #pragma unroll
  for (int j = 0; j < 16; ++j) {
    int e = base + j * 512 + t;
    bb[j] = -1;
    if (e < E) {
      int src = ei[e], dst = ei[E + e], rel = ea[e];
      key[j] = ((unsigned)(dst & (BNODES - 1)) << 20) | ((unsigned)src << 3) | (unsigned)rel;
      int b = dst >> 8;
      bb[j] = (short)b;
      atomicAdd(&hist[b], 1);
    }
  }
  __syncthreads();
  int v = hist[t];
  scanb[t] = v;
  __syncthreads();
  for (int d = 1; d < NBMAX; d <<= 1) {
    int w = (t >= d) ? scanb[t - d] : 0;
    __syncthreads();
    scanb[t] += w;
    __syncthreads();
  }
  startl[t] = scanb[t] - v;
  cursor[t] = scanb[t] - v;
  __syncthreads();
  #pragma unroll
  for (int j = 0; j < 16; ++j) {
    if (bb[j] >= 0) {
      int pos = atomicAdd(&cursor[bb[j]], 1);
      reorder[pos] = key[j];
      bkt[pos] = (unsigned short)bb[j];
    }
  }
  __syncthreads();
  if (t < NB && hist[t] > 0) gb[t] = atomicAdd(&gcursor[t], hist[t]);
  __syncthreads();
  for (int p = t; p < cn; p += 512) {
    int b = bkt[p];
    ebuf[gb[b] + (p - startl[b])] = reorder[p];
  }
}

// --- per-bucket counting sort by (dl,rel) with per-dst 8-aligned padding ---
__global__ __launch_bounds__(512) void k_sort(const int* __restrict__ bbase,
    const unsigned* __restrict__ ebuf, unsigned* __restrict__ ebuf2,
    float* __restrict__ wbuf, int* __restrict__ rps, int* __restrict__ rpc,
    int NB) {
  __shared__ int hist[2048];
  __shared__ float invw[2048];
  __shared__ int dlc[256];
  __shared__ unsigned sorted[SORTCAP];
  int t = threadIdx.x;
  int b = blockIdx.x;
  int s = bbase[b], e = bbase[b + 1];
  int out_s = ((s + 7) & ~7) + (b << 11);   // 8-aligned bucket base with pad slack
  for (int i = t; i < 2048; i += 512) hist[i] = 0;
  __syncthreads();
  for (int p = s + t; p < e; p += 512) {
    unsigned k = ebuf[p];
    atomicAdd(&hist[((k >> 20) << 3) | (k & 7u)], 1);
  }
  __syncthreads();
  for (int i = t; i < 2048; i += 512) {
    int c = hist[i];
    invw[i] = 1.0f / (float)(c > 1 ? c : 1);
  }
  __syncthreads();
  int pr[8];
  int cdl = 0, pc = 0;
  if (t < 256) {
    #pragma unroll
    for (int r = 0; r < 8; ++r) { pr[r] = cdl; cdl += hist[8 * t + r]; }
    pc = (cdl + 7) & ~7;
    dlc[t] = pc;
  }
  __syncthreads();
  for (int d = 1; d < 256; d <<= 1) {
    int w = (t < 256 && t >= d) ? dlc[t - d] : 0;
    __syncthreads();
    if (t < 256) dlc[t] += w;
    __syncthreads();
  }
  if (t < 256) {
    int ebase = dlc[t] - pc;
    #pragma unroll
    for (int r = 0; r < 8; ++r) hist[8 * t + r] = ebase + pr[r];
    rps[(b << 8) + t] = out_s + ebase;
    rpc[(b << 8) + t] = cdl;
  }
  __syncthreads();
  int ptot = dlc[255];
  if (ptot <= SORTCAP) {
    for (int p = t; p < ptot; p += 512) sorted[p] = 0xFFFFFFFFu;
    __syncthreads();
    for (int p = s + t; p < e; p += 512) {
      unsigned k = ebuf[p];
      int pos = atomicAdd(&hist[((k >> 20) << 3) | (k & 7u)], 1);
      sorted[pos] = k;
    }
    __syncthreads();
    for (int p = t; p < ptot; p += 512) {
      unsigned k = sorted[p];
      int o = out_s + p;
      if (k == 0xFFFFFFFFu) { ebuf2[o] = 0u; wbuf[o] = 0.f; }
      else { ebuf2[o] = k; wbuf[o] = invw[((k >> 20) << 3) | (k & 7u)]; }
    }
  } else {
    if (t < 256) {
      int ebase = dlc[t] - pc;
      for (int p = ebase + cdl; p < dlc[t]; ++p) {
        ebuf2[out_s + p] = 0u; wbuf[out_s + p] = 0.f;
      }
    }
    __syncthreads();
    for (int p = s + t; p < e; p += 512) {
      unsigned k = ebuf[p];
      int bin = ((k >> 20) << 3) | (k & 7u);
      int pos = atomicAdd(&hist[bin], 1);
      ebuf2[out_s + pos] = k;
      wbuf[out_s + pos] = invw[bin];
    }
  }
}

// --- build padded col-major bf16 weight panels ---
// Wcat[c][kk], stride 136: c<256: W1[c>>5][kk][c&31]; c>=256: root1[kk][c-256]; kk>=128 pad 0
// W2cat[c][kk], stride 40:  c<128: W2[c>>4][kk][c&15]; c>=128: root2[kk][c-128]; kk>=32 pad 0
__global__ __launch_bounds__(256) void k_prepw(const float* __restrict__ W1,
    const float* __restrict__ root1, const float* __restrict__ W2,
    const float* __restrict__ root2, unsigned short* __restrict__ Wcat,
    unsigned short* __restrict__ W2cat) {
  int id = blockIdx.x * 256 + threadIdx.x;
  union { __hip_bfloat16 h; unsigned short u; } cv;
  if (id < W1ELTS) {
    int c = id / W1STR, kk = id - c * W1STR;
    float v = 0.f;
    if (kk < FIN)
      v = (c < 256) ? W1[((size_t)(c >> 5) * FIN + kk) * HH1 + (c & 31)]
                    : root1[(size_t)kk * HH1 + (c - 256)];
    cv.h = __float2bfloat16(v);
    Wcat[id] = cv.u;
  } else if (id < W1ELTS + W2ELTS) {
    int id2 = id - W1ELTS;
    int c = id2 / W2STR, kk = id2 - c * W2STR;
    float v = 0.f;
    if (kk < HH1)
      v = (c < 128) ? W2[((size_t)(c >> 4) * HH1 + kk) * HH2 + (c & 15)]
                    : root2[(size_t)kk * HH2 + (c - 128)];
    cv.h = __float2bfloat16(v);
    W2cat[id2] = cv.u;
  }
}

// --- MFMA gemm1 with LDS-staged weights: per wave 32 rows x 288 cols ---
__global__ __launch_bounds__(256) void k_gemm1m(const float* __restrict__ x,
    const unsigned short* __restrict__ Wcat, const float* __restrict__ b1,
    __hip_bfloat16* __restrict__ xw, float* __restrict__ agg, int N) {
  __shared__ short WL[W1ELTS];          // 78336 B
  int t = threadIdx.x;
  for (int i = t; i < W1ELTS / 8; i += 256)
    ((uint4*)WL)[i] = ((const uint4*)Wcat)[i];
  __syncthreads();
  int lane = t & 63;
  int wv = t >> 6;
  int g = lane >> 4, lc = lane & 15;
  long nb = (long)blockIdx.x * 128 + wv * 32;
  f32x4 acc[2][18];
  #pragma unroll
  for (int m = 0; m < 2; ++m)
    #pragma unroll
    for (int j = 0; j < 18; ++j)
      acc[m][j] = (f32x4){0.f, 0.f, 0.f, 0.f};
  long rowA0 = nb + lc;       if (rowA0 > N - 1) rowA0 = N - 1;
  long rowA1 = nb + 16 + lc;  if (rowA1 > N - 1) rowA1 = N - 1;
  #pragma unroll
  for (int ks = 0; ks < 4; ++ks) {
    int ko = ks * 32 + g * 8;
    bf16x8 a0 = cvt8(x + rowA0 * FIN + ko);
    bf16x8 a1 = cvt8(x + rowA1 * FIN + ko);
    #pragma unroll
    for (int j = 0; j < 18; ++j) {
      bf16x8 bf = *(const bf16x8*)(WL + (16 * j + lc) * W1STR + ko);
      acc[0][j] = __builtin_amdgcn_mfma_f32_16x16x32_bf16(a0, bf, acc[0][j], 0, 0, 0);
      acc[1][j] = __builtin_amdgcn_mfma_f32_16x16x32_bf16(a1, bf, acc[1][j], 0, 0, 0);
    }
  }
  #pragma unroll
  for (int m = 0; m < 2; ++m) {
    #pragma unroll
    for (int j = 0; j < 18; ++j) {
      #pragma unroll
      for (int q = 0; q < 4; ++q) {
        long row = nb + 16 * m + g * 4 + q;
        if (row < N) {
          if (j < 16) {
            xw[row * 256 + 16 * j + lc] = __float2bfloat16(acc[m][j][q]);
          } else {
            int cc = (j - 16) * 16 + lc;
            agg[row * HH1 + cc] = acc[m][j][q] + b1[cc];
          }
        }
      }
    }
  }
}

// layer-1 aggregation: one wave64 per dst; 32 h-lanes x 2 edge-substreams
__global__ __launch_bounds__(256) void k_agg1(const int* __restrict__ rps,
    const int* __restrict__ rpc, const unsigned* __restrict__ eb,
    const float* __restrict__ wb, const __hip_bfloat16* __restrict__ xw,
    float* __restrict__ agg, int N) {
  int d = blockIdx.x * 4 + (threadIdx.x >> 6);
  if (d >= N) return;
  int lane = threadIdx.x & 63;
  int h = lane & 31, half = lane >> 5;
  int s = rps[d];
  int cnt = rpc[d];
  float acc = 0.f;
  for (int j = half * 8; j < cnt; j += 16) {
    const unsigned* kp = eb + s + j;
    uint4 ka = *(const uint4*)kp;
    uint4 kb = *(const uint4*)(kp + 4);
    float4 wa = *(const float4*)(wb + s + j);
    float4 wc = *(const float4*)(wb + s + j + 4);
    unsigned ks[8] = {ka.x, ka.y, ka.z, ka.w, kb.x, kb.y, kb.z, kb.w};
    float ws[8] = {wa.x, wa.y, wa.z, wa.w, wc.x, wc.y, wc.z, wc.w};
    #pragma unroll
    for (int u = 0; u < 8; ++u) {
      unsigned idx = ks[u] & 0xFFFFFu;
      float v = __bfloat162float(xw[((size_t)idx << 5) + h]);
      acc = fmaf(ws[u], v, acc);
    }
  }
  acc += __shfl_xor(acc, 32);
  if (half == 0) agg[((size_t)d << 5) + h] += acc;
}

// --- MFMA gemm2 with LDS-staged weights: per wave 32 rows x 144 cols, K=32 ---
__global__ __launch_bounds__(256) void k_gemm2m(const float* __restrict__ agg1,
    const unsigned short* __restrict__ W2cat, const float* __restrict__ b2,
    __hip_bfloat16* __restrict__ xw, float* __restrict__ agg, int N) {
  __shared__ short WL[W2ELTS];          // 11520 B
  int t = threadIdx.x;
  for (int i = t; i < W2ELTS / 8; i += 256)
    ((uint4*)WL)[i] = ((const uint4*)W2cat)[i];
  __syncthreads();
  int lane = t & 63;
  int wv = t >> 6;
  int g = lane >> 4, lc = lane & 15;
  long nb = (long)blockIdx.x * 128 + wv * 32;
  f32x4 acc[2][9];
  #pragma unroll
  for (int m = 0; m < 2; ++m)
    #pragma unroll
    for (int j = 0; j < 9; ++j)
      acc[m][j] = (f32x4){0.f, 0.f, 0.f, 0.f};
  long rowA0 = nb + lc;       if (rowA0 > N - 1) rowA0 = N - 1;
  long rowA1 = nb + 16 + lc;  if (rowA1 > N - 1) rowA1 = N - 1;
  bf16x8 a0 = cvt8relu(agg1 + rowA0 * HH1 + g * 8);
  bf16x8 a1 = cvt8relu(agg1 + rowA1 * HH1 + g * 8);
  #pragma unroll
  for (int j = 0; j < 9; ++j) {
    bf16x8 bf = *(const bf16x8*)(WL + (16 * j + lc) * W2STR + g * 8);
    acc[0][j] = __builtin_amdgcn_mfma_f32_16x16x32_bf16(a0, bf, acc[0][j], 0, 0, 0);
    acc[1][j] = __builtin_amdgcn_mfma_f32_16x16x32_bf16(a1, bf, acc[1][j], 0, 0, 0);
  }
  #pragma unroll
  for (int m = 0; m < 2; ++m) {
    #pragma unroll
    for (int j = 0; j < 9; ++j) {
      #pragma unroll
      for (int q = 0; q < 4; ++q) {
        long row = nb + 16 * m + g * 4 + q;
        if (row < N) {
          if (j < 8) {
            xw[row * 128 + 16 * j + lc] = __float2bfloat16(acc[m][j][q]);
          } else {
            agg[row * HH2 + lc] = acc[m][j][q] + b2[lc];
          }
        }
      }
    }
  }
}

// layer-2 aggregation: one wave64 per dst; 16 h-lanes x 4 edge-substreams
__global__ __launch_bounds__(256) void k_agg2(const int* __restrict__ rps,
    const int* __restrict__ rpc, const unsigned* __restrict__ eb,
    const float* __restrict__ wb, const __hip_bfloat16* __restrict__ xw,
    float* __restrict__ agg, int N) {
  int d = blockIdx.x * 4 + (threadIdx.x >> 6);
  if (d >= N) return;
  int lane = threadIdx.x & 63;
  int h = lane & 15, q = lane >> 4;
  int s = rps[d];
  int cnt = rpc[d];
  float acc = 0.f;
  for (int j = q * 8; j < cnt; j += 32) {
    const unsigned* kp = eb + s + j;
    uint4 ka = *(const uint4*)kp;
    uint4 kb = *(const uint4*)(kp + 4);
    float4 wa = *(const float4*)(wb + s + j);
    float4 wc = *(const float4*)(wb + s + j + 4);
    unsigned ks[8] = {ka.x, ka.y, ka.z, ka.w, kb.x, kb.y, kb.z, kb.w};
    float ws[8] = {wa.x, wa.y, wa.z, wa.w, wc.x, wc.y, wc.z, wc.w};
    #pragma unroll
    for (int u = 0; u < 8; ++u) {
      unsigned idx = ks[u] & 0xFFFFFu;
      float v = __bfloat162float(xw[((size_t)idx << 4) + h]);
      acc = fmaf(ws[u], v, acc);
    }
  }
  acc += __shfl_xor(acc, 32);
  acc += __shfl_xor(acc, 16);
  if (q == 0) agg[((size_t)d << 4) + h] += acc;
}

__global__ __launch_bounds__(256) void k_pool(const float* __restrict__ agg2,
    const int* __restrict__ batch, unsigned* __restrict__ pooled, int N) {
  int gid = blockIdx.x * 256 + threadIdx.x;
  int n = gid >> 4;
  if (n < N) {
    int h = gid & 15;
    float v = fmaxf(agg2[(size_t)n * HH2 + h], 0.f);
    atomicMax(&pooled[batch[n] * HH2 + h], __float_as_uint(v));
  }
}

__global__ __launch_bounds__(256) void k_dense(const float* __restrict__ pooled,
    const float* __restrict__ dw, const float* __restrict__ db,
    float* __restrict__ out, int Gn) {
  int g = blockIdx.x * 256 + threadIdx.x;
  if (g < Gn) {
    float s = db[0];
    #pragma unroll
    for (int h = 0; h < HH2; ++h) s += pooled[(size_t)g * HH2 + h] * dw[h];
    out[g] = s;
  }
}

extern "C" void kernel_launch(void* const* d_in, const int* in_sizes, int n_in,
                              void* d_out, int out_size, void* d_ws, size_t ws_size,
                              hipStream_t stream) {
  const float* x     = (const float*)d_in[0];
  const int*   ei    = (const int*)d_in[1];
  const int*   ea    = (const int*)d_in[2];
  const int*   batch = (const int*)d_in[3];
  const float* W1    = (const float*)d_in[4];
  const float* root1 = (const float*)d_in[5];
  const float* b1    = (const float*)d_in[6];
  const float* W2    = (const float*)d_in[7];
  const float* root2 = (const float*)d_in[8];
  const float* b2    = (const float*)d_in[9];
  const float* dw    = (const float*)d_in[10];
  const float* db    = (const float*)d_in[11];
  float* out = (float*)d_out;

  const int N  = in_sizes[0] / FIN;
  const int E  = in_sizes[2];
  const int Gn = out_size;
  const int NB = (N + BNODES - 1) / BNODES;   // 391 for N=100000

  char* ws = (char*)d_ws;
  size_t off = 0;
  auto walloc = [&](size_t bytes) -> void* {
    void* p = (void*)(ws + off);
    off += (bytes + 255) & ~(size_t)255;
    return p;
  };
  const size_t EP = (size_t)E + (size_t)NBMAX * 2048 + 64;  // padded edge capacity
  int*            ghist   = (int*)            walloc((size_t)NBMAX * 4);
  int*            bbase   = (int*)            walloc(((size_t)NBMAX + 1) * 4);
  int*            gcursor = (int*)            walloc((size_t)NBMAX * 4);
  unsigned*       ebuf    = (unsigned*)       walloc((size_t)E * 4);
  unsigned*       ebuf2   = (unsigned*)       walloc(EP * 4);
  float*          wbuf    = (float*)          walloc(EP * 4);
  int*            rps     = (int*)            walloc((size_t)NBMAX * 256 * 4);
  int*            rpc     = (int*)            walloc((size_t)NBMAX * 256 * 4);
  unsigned short* Wcat    = (unsigned short*) walloc((size_t)W1ELTS * 2);
  unsigned short* W2cat   = (unsigned short*) walloc((size_t)W2ELTS * 2);
  __hip_bfloat16* xw1     = (__hip_bfloat16*) walloc((size_t)N * RNUM * HH1 * 2);
  float*          agg1    = (float*)          walloc((size_t)N * HH1 * 4);
  __hip_bfloat16* xw2     = (__hip_bfloat16*) walloc((size_t)N * RNUM * HH2 * 2);
  float*          agg2    = (float*)          walloc((size_t)N * HH2 * 4);
  unsigned*       pooled  = (unsigned*)       walloc((size_t)Gn * HH2 * 4);

  hipMemsetAsync(ghist, 0, (size_t)NBMAX * 4, stream);
  hipMemsetAsync(pooled, 0, (size_t)Gn * HH2 * 4, stream);

  k_prepw<<<(W1ELTS + W2ELTS + 255) / 256, 256, 0, stream>>>(W1, root1, W2, root2, Wcat, W2cat);
  k_bhist<<<(E + 4095) / 4096, 256, 0, stream>>>(ei, ghist, E, NB);
  k_bscan<<<1, NBMAX, 0, stream>>>(ghist, bbase, gcursor, NB, E);
  k_part<<<(E + PCHUNK - 1) / PCHUNK, 512, 0, stream>>>(ei, ea, gcursor, ebuf, E, NB);
  k_sort<<<NB, 512, 0, stream>>>(bbase, ebuf, ebuf2, wbuf, rps, rpc, NB);

  k_gemm1m<<<(N + 127) / 128, 256, 0, stream>>>(x, Wcat, b1, xw1, agg1, N);
  k_agg1<<<(N + 3) / 4, 256, 0, stream>>>(rps, rpc, ebuf2, wbuf, xw1, agg1, N);
  k_gemm2m<<<(N + 127) / 128, 256, 0, stream>>>(agg1, W2cat, b2, xw2, agg2, N);
  k_agg2<<<(N + 3) / 4, 256, 0, stream>>>(rps, rpc, ebuf2, wbuf, xw2, agg2, N);
  k_pool<<<(int)(((long)N * HH2 + 255) / 256), 256, 0, stream>>>(agg2, batch, pooled, N);
  k_dense<<<(Gn + 255) / 256, 256, 0, stream>>>((const float*)pooled, dw, db, out, Gn);
}